// Round 2
// baseline (1535.652 us; speedup 1.0000x reference)
//
#include <hip/hip_runtime.h>
#include <hip/hip_bf16.h>
#include <cstdint>
#include <cstddef>

#define N_NODES 20000
#define N_EDGES 40000
#define N_GRAPHS 800
#define ATOM 64
#define CONV 128
#define KTOT 8256              // 128 c * 64 d + 64 bias rows
#define MLP1D 512
#define MLP2D 256
#define NOUT 34

typedef unsigned short u16;
typedef short short8 __attribute__((ext_vector_type(8)));
typedef float f32x4 __attribute__((ext_vector_type(4)));

__device__ __forceinline__ float bf2f(u16 u) {
    union { unsigned int i; float f; } v; v.i = ((unsigned int)u) << 16; return v.f;
}
__device__ __forceinline__ u16 f2bf(float f) {
    union { float f; unsigned int i; } v; v.f = f;
    unsigned int r = v.i + 0x7FFFu + ((v.i >> 16) & 1u);
    return (u16)(r >> 16);
}
__device__ __forceinline__ short fbf(float f) {
    union { __hip_bfloat16 b; short s; } u;
    u.b = __float2bfloat16(f);
    return u.s;
}
__device__ __forceinline__ float sigm(float x) { return 1.f / (1.f + expf(-x)); }

// ---------------- small prep kernels ----------------

// dst[c*rows + r] = src[r*cols + c]
__global__ void transpose_f32(float* __restrict__ dst, const float* __restrict__ src,
                              int rows, int cols) {
    int i = blockIdx.x * 256 + threadIdx.x;
    if (i >= rows * cols) return;
    int r = i / cols, c = i % cols;
    dst[c * rows + r] = src[i];
}

// Build We2RT hi/lo [64 f][KTOT k]: k<8192 -> We2[k>>6, (k&63)*64+f]; k>=8192 -> b_e2[(k-8192)*64+f]
__global__ void we2rt_kernel(u16* __restrict__ hi, u16* __restrict__ lo,
                             const float* __restrict__ We2, const float* __restrict__ be2) {
    int f = blockIdx.y;
    int k = blockIdx.x * 256 + threadIdx.x;
    if (k >= KTOT) return;
    float v;
    if (k < 8192) v = We2[(size_t)(k >> 6) * 4096 + (size_t)(k & 63) * 64 + f];
    else          v = be2[(size_t)(k - 8192) * 64 + f];
    u16 h = f2bf(v);
    hi[(size_t)f * KTOT + k] = h;
    lo[(size_t)f * KTOT + k] = f2bf(v - bf2f(h));
}

// x = relu(x_feat @ W_lin + b_lin), 4 nodes/block
__global__ __launch_bounds__(256) void lin_kernel(const float* __restrict__ xf,
    const float* __restrict__ W, const float* __restrict__ b, float* __restrict__ hx) {
    __shared__ float xr[4][64];
    int ln = threadIdx.x >> 6, j = threadIdx.x & 63;
    int n = (blockIdx.x << 2) + ln;
    xr[ln][j] = xf[(size_t)n * 64 + j];
    __syncthreads();
    float acc = b[j];
    for (int i = 0; i < 64; ++i) acc = fmaf(xr[ln][i], W[i * 64 + j], acc);
    hx[(size_t)n * 64 + j] = fmaxf(acc, 0.f);
}

// he = relu(edge_attr @ W_e1 + b_e1) -> bf16, 2 edges/block
__global__ __launch_bounds__(256) void he_kernel(const float* __restrict__ ea,
    const float* __restrict__ W, const float* __restrict__ b, u16* __restrict__ he) {
    __shared__ float er[2][16];
    int ln = threadIdx.x >> 7, c = threadIdx.x & 127;
    int e = (blockIdx.x << 1) + ln;
    if (c < 16) er[ln][c] = ea[(size_t)e * 16 + c];
    __syncthreads();
    float acc = b[c];
    for (int i = 0; i < 16; ++i) acc = fmaf(er[ln][i], W[i * 128 + c], acc);
    he[(size_t)e * 128 + c] = f2bf(fmaxf(acc, 0.f));
}

__global__ void deg_kernel(const int* __restrict__ dst, float* __restrict__ deg) {
    int i = blockIdx.x * 256 + threadIdx.x;
    if (i < N_EDGES) atomicAdd(&deg[dst[i]], 1.f);
}

__global__ void gstart_kernel(const int* __restrict__ batch, int* __restrict__ gstart) {
    int g = blockIdx.x * 256 + threadIdx.x;
    if (g > N_GRAPHS) return;
    if (g == N_GRAPHS) { gstart[g] = N_NODES; return; }
    int lo = 0, hi = N_NODES;
    while (lo < hi) { int mid = (lo + hi) >> 1; if (batch[mid] < g) lo = mid + 1; else hi = mid; }
    gstart[g] = lo;
}

// ---------------- fused message GEMM ----------------
// agg[dst_e, f] += sum_k U[e,k] * We2R[k,f],  U[e, c*64+d] = he[e,c]*x[src_e,d]
// (c==128 is the virtual bias row: he=1, We2R rows 8192..8255 = b_e2 reshaped)
// Block: 256 thr = 4 waves x 32 edge-rows; M-tile 128 edges; N = 64 (full);
// K split 4-ways over c across blockIdx.x; partial sums land in agg via atomics.
__global__ __launch_bounds__(256) void msg_fused(
    const u16* __restrict__ he,      // [E][128] bf16
    const u16* __restrict__ Bh,      // We2RT hi [64][KTOT]
    const u16* __restrict__ Bl,      // We2RT lo
    const float* __restrict__ x,     // [N][64] f32
    const int* __restrict__ src, const int* __restrict__ dst,
    float* __restrict__ agg) {
    __shared__ u16 heT[33 * 128];    // [cLoc][row]
    int ks = blockIdx.x;             // 0..3
    int mt = blockIdx.y;             // 0..312
    int m0 = mt << 7;
    int c0 = (129 * ks) >> 2;
    int c1 = (129 * (ks + 1)) >> 2;
    int nc = c1 - c0;                // 32 or 33
    int tid = threadIdx.x;

    // stage heT[cLoc][row] (coalesced-ish global reads, transposed LDS write)
    for (int idx = tid; idx < nc * 128; idx += 256) {
        int r = idx / nc, c = idx - r * nc;
        int cg = c0 + c;
        int e = m0 + r;
        u16 v;
        if (cg == 128) v = 0x3F80;                       // bias row: he = 1.0
        else if (e < N_EDGES) v = he[(size_t)e * 128 + cg];
        else v = 0;
        heT[c * 128 + r] = v;
    }

    int w = tid >> 6, lane = tid & 63;
    int lr = lane & 15, lk = lane >> 4;
    int wrow = w * 32;

    // preload x[src_e] fragments: per lane, rows {wrow+lr, wrow+16+lr},
    // d in {lk*8..lk*8+7} and {32+lk*8..32+lk*8+7}
    f32x4 xr[2][2][2];
    #pragma unroll
    for (int mi = 0; mi < 2; ++mi) {
        int e = m0 + wrow + mi * 16 + lr;
        int s = (e < N_EDGES) ? src[e] : 0;
        const float* xp = x + (size_t)s * 64;
        xr[mi][0][0] = *(const f32x4*)&xp[lk * 8];
        xr[mi][0][1] = *(const f32x4*)&xp[lk * 8 + 4];
        xr[mi][1][0] = *(const f32x4*)&xp[32 + lk * 8];
        xr[mi][1][1] = *(const f32x4*)&xp[32 + lk * 8 + 4];
    }

    size_t kbase = (size_t)c0 * 64 + lk * 8;
    const u16* bh0 = Bh + (size_t)(lr     ) * KTOT + kbase;
    const u16* bh1 = Bh + (size_t)(lr + 16) * KTOT + kbase;
    const u16* bh2 = Bh + (size_t)(lr + 32) * KTOT + kbase;
    const u16* bh3 = Bh + (size_t)(lr + 48) * KTOT + kbase;
    const u16* bl0 = Bl + (size_t)(lr     ) * KTOT + kbase;
    const u16* bl1 = Bl + (size_t)(lr + 16) * KTOT + kbase;
    const u16* bl2 = Bl + (size_t)(lr + 32) * KTOT + kbase;
    const u16* bl3 = Bl + (size_t)(lr + 48) * KTOT + kbase;

    f32x4 acc[2][4] = {};
    __syncthreads();

    for (int cc = 0; cc < nc; ++cc) {
        float hef0 = bf2f(heT[cc * 128 + wrow + lr]);
        float hef1 = bf2f(heT[cc * 128 + wrow + 16 + lr]);
        int kc = cc * 64;
        #pragma unroll
        for (int h = 0; h < 2; ++h) {
            int ko = kc + h * 32;
            short8 b0h = *(const short8*)(bh0 + ko);
            short8 b1h = *(const short8*)(bh1 + ko);
            short8 b2h = *(const short8*)(bh2 + ko);
            short8 b3h = *(const short8*)(bh3 + ko);
            short8 b0l = *(const short8*)(bl0 + ko);
            short8 b1l = *(const short8*)(bl1 + ko);
            short8 b2l = *(const short8*)(bl2 + ko);
            short8 b3l = *(const short8*)(bl3 + ko);
            short8 af0, af1;
            #pragma unroll
            for (int j = 0; j < 4; ++j) {
                af0[j]     = fbf(hef0 * xr[0][h][0][j]);
                af0[j + 4] = fbf(hef0 * xr[0][h][1][j]);
                af1[j]     = fbf(hef1 * xr[1][h][0][j]);
                af1[j + 4] = fbf(hef1 * xr[1][h][1][j]);
            }
            acc[0][0] = __builtin_amdgcn_mfma_f32_16x16x32_bf16(af0, b0h, acc[0][0], 0, 0, 0);
            acc[0][1] = __builtin_amdgcn_mfma_f32_16x16x32_bf16(af0, b1h, acc[0][1], 0, 0, 0);
            acc[0][2] = __builtin_amdgcn_mfma_f32_16x16x32_bf16(af0, b2h, acc[0][2], 0, 0, 0);
            acc[0][3] = __builtin_amdgcn_mfma_f32_16x16x32_bf16(af0, b3h, acc[0][3], 0, 0, 0);
            acc[1][0] = __builtin_amdgcn_mfma_f32_16x16x32_bf16(af1, b0h, acc[1][0], 0, 0, 0);
            acc[1][1] = __builtin_amdgcn_mfma_f32_16x16x32_bf16(af1, b1h, acc[1][1], 0, 0, 0);
            acc[1][2] = __builtin_amdgcn_mfma_f32_16x16x32_bf16(af1, b2h, acc[1][2], 0, 0, 0);
            acc[1][3] = __builtin_amdgcn_mfma_f32_16x16x32_bf16(af1, b3h, acc[1][3], 0, 0, 0);
            acc[0][0] = __builtin_amdgcn_mfma_f32_16x16x32_bf16(af0, b0l, acc[0][0], 0, 0, 0);
            acc[0][1] = __builtin_amdgcn_mfma_f32_16x16x32_bf16(af0, b1l, acc[0][1], 0, 0, 0);
            acc[0][2] = __builtin_amdgcn_mfma_f32_16x16x32_bf16(af0, b2l, acc[0][2], 0, 0, 0);
            acc[0][3] = __builtin_amdgcn_mfma_f32_16x16x32_bf16(af0, b3l, acc[0][3], 0, 0, 0);
            acc[1][0] = __builtin_amdgcn_mfma_f32_16x16x32_bf16(af1, b0l, acc[1][0], 0, 0, 0);
            acc[1][1] = __builtin_amdgcn_mfma_f32_16x16x32_bf16(af1, b1l, acc[1][1], 0, 0, 0);
            acc[1][2] = __builtin_amdgcn_mfma_f32_16x16x32_bf16(af1, b2l, acc[1][2], 0, 0, 0);
            acc[1][3] = __builtin_amdgcn_mfma_f32_16x16x32_bf16(af1, b3l, acc[1][3], 0, 0, 0);
        }
    }

    // epilogue: scatter partial msg into agg (C/D: col=lane&15, row=(lane>>4)*4+r2)
    #pragma unroll
    for (int mi = 0; mi < 2; ++mi) {
        int ebase = m0 + wrow + mi * 16 + lk * 4;
        #pragma unroll
        for (int r2 = 0; r2 < 4; ++r2) {
            int e = ebase + r2;
            if (e < N_EDGES) {
                int dv = dst[e];
                float* ap = agg + (size_t)dv * 64 + lr;
                atomicAdd(ap,      acc[mi][0][r2]);
                atomicAdd(ap + 16, acc[mi][1][r2]);
                atomicAdd(ap + 32, acc[mi][2][r2]);
                atomicAdd(ap + 48, acc[mi][3][r2]);
            }
        }
    }
}

// agg -> mean -> +b_conv -> relu -> GRU cell; updates hx in place. 4 nodes/block.
__global__ __launch_bounds__(256) void gru_kernel(const float* __restrict__ agg,
    const float* __restrict__ deg, const float* __restrict__ bconv,
    const float* __restrict__ WihT, const float* __restrict__ WhhT,   // [64][192]
    const float* __restrict__ bih, const float* __restrict__ bhh,
    float* __restrict__ hx) {
    __shared__ float mh[4][2][64];
    int ln = threadIdx.x >> 6, j = threadIdx.x & 63;
    int n = (blockIdx.x << 2) + ln;
    float dg = fmaxf(deg[n], 1.f);
    float m = fmaxf(agg[(size_t)n * 64 + j] / dg + bconv[j], 0.f);
    float h = hx[(size_t)n * 64 + j];
    mh[ln][0][j] = m; mh[ln][1][j] = h;
    __syncthreads();
    float gri = bih[j], gzi = bih[64 + j], gni = bih[128 + j];
    float grh = bhh[j], gzh = bhh[64 + j], gnh = bhh[128 + j];
    for (int i = 0; i < 64; ++i) {
        float mi = mh[ln][0][i], hi = mh[ln][1][i];
        gri = fmaf(mi, WihT[i * 192 + j], gri);
        gzi = fmaf(mi, WihT[i * 192 + 64 + j], gzi);
        gni = fmaf(mi, WihT[i * 192 + 128 + j], gni);
        grh = fmaf(hi, WhhT[i * 192 + j], grh);
        gzh = fmaf(hi, WhhT[i * 192 + 64 + j], gzh);
        gnh = fmaf(hi, WhhT[i * 192 + 128 + j], gnh);
    }
    float rr = sigm(gri + grh);
    float zz = sigm(gzi + gzh);
    float nn = tanhf(gni + rr * gnh);
    hx[(size_t)n * 64 + j] = (1.f - zz) * nn + zz * h;
}

// ---------------- Set2Set ----------------
__global__ void lstm_kernel(const float* __restrict__ WihT,  // [128][256]
    const float* __restrict__ WhhT,                          // [64][256]
    const float* __restrict__ bih, const float* __restrict__ bhh,
    float* __restrict__ qstar, float* __restrict__ hl, float* __restrict__ cl) {
    __shared__ float qs[128], hs[64];
    int g = blockIdx.x, j = threadIdx.x;
    qs[j] = qstar[g * 128 + j];
    qs[64 + j] = qstar[g * 128 + 64 + j];
    hs[j] = hl[g * 64 + j];
    __syncthreads();
    float g0 = bih[j] + bhh[j];
    float g1 = bih[64 + j] + bhh[64 + j];
    float g2 = bih[128 + j] + bhh[128 + j];
    float g3 = bih[192 + j] + bhh[192 + j];
    for (int i = 0; i < 128; ++i) {
        float q = qs[i];
        g0 = fmaf(q, WihT[i * 256 + j], g0);
        g1 = fmaf(q, WihT[i * 256 + 64 + j], g1);
        g2 = fmaf(q, WihT[i * 256 + 128 + j], g2);
        g3 = fmaf(q, WihT[i * 256 + 192 + j], g3);
    }
    for (int i = 0; i < 64; ++i) {
        float hh = hs[i];
        g0 = fmaf(hh, WhhT[i * 256 + j], g0);
        g1 = fmaf(hh, WhhT[i * 256 + 64 + j], g1);
        g2 = fmaf(hh, WhhT[i * 256 + 128 + j], g2);
        g3 = fmaf(hh, WhhT[i * 256 + 192 + j], g3);
    }
    float ig = sigm(g0), fg = sigm(g1), cg = tanhf(g2), og = sigm(g3);
    float c = fg * cl[g * 64 + j] + ig * cg;
    cl[g * 64 + j] = c;
    float h = og * tanhf(c);
    hl[g * 64 + j] = h;
    qstar[g * 128 + j] = h;   // q part
}

// per-graph softmax attention readout; one wave per graph
__global__ void attn_kernel(const float* __restrict__ x, float* __restrict__ qstar,
                            const int* __restrict__ gstart) {
    int g = blockIdx.x, l = threadIdx.x;
    int s0 = gstart[g], s1 = gstart[g + 1];
    float q = qstar[g * 128 + l];
    float emax = -3.0e38f;
    for (int n = s0; n < s1; ++n) {
        float v = x[(size_t)n * 64 + l] * q;
        for (int o = 32; o; o >>= 1) v += __shfl_xor(v, o);
        emax = fmaxf(emax, v);
    }
    float esum = 0.f, racc = 0.f;
    for (int n = s0; n < s1; ++n) {
        float xv = x[(size_t)n * 64 + l];
        float v = xv * q;
        for (int o = 32; o; o >>= 1) v += __shfl_xor(v, o);
        float ww = expf(v - emax);
        esum += ww;
        racc = fmaf(ww, xv, racc);
    }
    qstar[g * 128 + 64 + l] = (s1 > s0) ? (racc / esum) : 0.f;
}

// ---------------- head ----------------
__global__ void bn_kernel(const float* __restrict__ qs, const float* __restrict__ gamma,
                          const float* __restrict__ beta, float* __restrict__ out) {
    int c = blockIdx.x, l = threadIdx.x;
    float s = 0.f, ss = 0.f;
    for (int r = l; r < N_GRAPHS; r += 64) {
        float v = qs[r * 128 + c];
        s += v; ss += v * v;
    }
    for (int o = 32; o; o >>= 1) { s += __shfl_xor(s, o); ss += __shfl_xor(ss, o); }
    float mu = s * (1.f / N_GRAPHS);
    float var = ss * (1.f / N_GRAPHS) - mu * mu;
    float inv = rsqrtf(var + 1e-5f);
    float ga = gamma[c], be = beta[c];
    for (int r = l; r < N_GRAPHS; r += 64)
        out[r * 128 + c] = ga * (qs[r * 128 + c] - mu) * inv + be;
}

__global__ __launch_bounds__(256) void mlp1_kernel(const float* __restrict__ in,
    const float* __restrict__ W, const float* __restrict__ b, float* __restrict__ out) {
    __shared__ float row[128];
    int r = blockIdx.x, o = blockIdx.y * 256 + threadIdx.x;
    if (threadIdx.x < 128) row[threadIdx.x] = in[r * 128 + threadIdx.x];
    __syncthreads();
    float acc = b[o];
    for (int i = 0; i < 128; ++i) acc = fmaf(row[i], W[i * MLP1D + o], acc);
    out[r * MLP1D + o] = fmaxf(acc, 0.f);
}

__global__ __launch_bounds__(256) void mlp2_kernel(const float* __restrict__ in,
    const float* __restrict__ W, const float* __restrict__ b, float* __restrict__ out) {
    __shared__ float row[512];
    int r = blockIdx.x, t = threadIdx.x;
    row[t] = in[r * MLP1D + t];
    row[256 + t] = in[r * MLP1D + 256 + t];
    __syncthreads();
    float acc = b[t];
    for (int i = 0; i < 512; ++i) acc = fmaf(row[i], W[i * MLP2D + t], acc);
    out[r * MLP2D + t] = fmaxf(acc, 0.f);
}

__global__ void pred_kernel(const float* __restrict__ y2, const float* __restrict__ W,
    const float* __restrict__ b, float* __restrict__ out) {
    __shared__ float row[256];
    int r = blockIdx.x, t = threadIdx.x;
    for (int i = t; i < 256; i += 64) row[i] = y2[r * MLP2D + i];
    __syncthreads();
    if (t < NOUT) {
        float acc = b[t];
        for (int i = 0; i < 256; ++i) acc = fmaf(row[i], W[i * NOUT + t], acc);
        out[r * NOUT + t] = acc;
    }
}

// ---------------- launch ----------------
extern "C" void kernel_launch(void* const* d_in, const int* in_sizes, int n_in,
                              void* d_out, int out_size, void* d_ws, size_t ws_size,
                              hipStream_t stream) {
    (void)in_sizes; (void)n_in; (void)out_size; (void)ws_size;
    const float* x_feat    = (const float*)d_in[0];
    const float* edge_attr = (const float*)d_in[1];
    const int*   eidx      = (const int*)d_in[2];
    const int*   batch     = (const int*)d_in[3];
    const float* W_lin = (const float*)d_in[4];
    const float* b_lin = (const float*)d_in[5];
    const float* W_e1  = (const float*)d_in[6];
    const float* b_e1  = (const float*)d_in[7];
    const float* W_e2  = (const float*)d_in[8];
    const float* b_e2  = (const float*)d_in[9];
    const float* b_conv= (const float*)d_in[10];
    const float* gWih  = (const float*)d_in[11];
    const float* gWhh  = (const float*)d_in[12];
    const float* gbih  = (const float*)d_in[13];
    const float* gbhh  = (const float*)d_in[14];
    const float* lWih  = (const float*)d_in[15];
    const float* lWhh  = (const float*)d_in[16];
    const float* lbih  = (const float*)d_in[17];
    const float* lbhh  = (const float*)d_in[18];
    const float* bng   = (const float*)d_in[19];
    const float* bnb   = (const float*)d_in[20];
    const float* Wm1   = (const float*)d_in[21];
    const float* bm1   = (const float*)d_in[22];
    const float* Wm2   = (const float*)d_in[23];
    const float* bm2   = (const float*)d_in[24];
    const float* Wp    = (const float*)d_in[25];
    const float* bp    = (const float*)d_in[26];
    float* out = (float*)d_out;

    const int* src = eidx;
    const int* dst = eidx + N_EDGES;

    char* w = (char*)d_ws;
    size_t off = 0;
    auto alloc = [&](size_t bytes) -> char* {
        char* p = w + off; off += (bytes + 255) & ~(size_t)255; return p;
    };
    u16*   he    = (u16*)alloc((size_t)N_EDGES * CONV * 2);      // 10.24 MB
    u16*   Bh    = (u16*)alloc((size_t)64 * KTOT * 2);           // 1.06 MB
    u16*   Bl    = (u16*)alloc((size_t)64 * KTOT * 2);           // 1.06 MB
    float* hx    = (float*)alloc((size_t)N_NODES * ATOM * 4);    // 5.12 MB
    float* agg   = (float*)alloc((size_t)N_NODES * ATOM * 4);    // 5.12 MB
    float* deg   = (float*)alloc((size_t)N_NODES * 4);
    float* gWihT = (float*)alloc(192 * 64 * 4);
    float* gWhhT = (float*)alloc(192 * 64 * 4);
    float* lWihT = (float*)alloc(256 * 128 * 4);
    float* lWhhT = (float*)alloc(256 * 64 * 4);
    float* qstar = (float*)alloc((size_t)N_GRAPHS * 128 * 4);
    float* hl    = (float*)alloc((size_t)N_GRAPHS * 64 * 4);
    float* cl    = (float*)alloc((size_t)N_GRAPHS * 64 * 4);
    int*   gst   = (int*)alloc((N_GRAPHS + 1) * 4);
    float* bno   = (float*)alloc((size_t)N_GRAPHS * 128 * 4);
    float* y1    = (float*)alloc((size_t)N_GRAPHS * MLP1D * 4);
    float* y2    = (float*)alloc((size_t)N_GRAPHS * MLP2D * 4);
    // total ~23.3 MB

    hipMemsetAsync(deg, 0, (size_t)N_NODES * 4, stream);
    hipMemsetAsync(qstar, 0, (size_t)N_GRAPHS * 128 * 4, stream);
    hipMemsetAsync(hl, 0, (size_t)N_GRAPHS * 64 * 4, stream);
    hipMemsetAsync(cl, 0, (size_t)N_GRAPHS * 64 * 4, stream);

    transpose_f32<<<(192 * 64 + 255) / 256, 256, 0, stream>>>(gWihT, gWih, 192, 64);
    transpose_f32<<<(192 * 64 + 255) / 256, 256, 0, stream>>>(gWhhT, gWhh, 192, 64);
    transpose_f32<<<(256 * 128 + 255) / 256, 256, 0, stream>>>(lWihT, lWih, 256, 128);
    transpose_f32<<<(256 * 64 + 255) / 256, 256, 0, stream>>>(lWhhT, lWhh, 256, 64);
    we2rt_kernel<<<dim3((KTOT + 255) / 256, 64), 256, 0, stream>>>(Bh, Bl, W_e2, b_e2);
    lin_kernel<<<N_NODES / 4, 256, 0, stream>>>(x_feat, W_lin, b_lin, hx);
    he_kernel<<<N_EDGES / 2, 256, 0, stream>>>(edge_attr, W_e1, b_e1, he);
    deg_kernel<<<(N_EDGES + 255) / 256, 256, 0, stream>>>(dst, deg);

    const int MTILES = (N_EDGES + 127) / 128;   // 313
    for (int r = 0; r < 3; ++r) {
        hipMemsetAsync(agg, 0, (size_t)N_NODES * ATOM * 4, stream);
        msg_fused<<<dim3(4, MTILES), 256, 0, stream>>>(he, Bh, Bl, hx, src, dst, agg);
        gru_kernel<<<N_NODES / 4, 256, 0, stream>>>(agg, deg, b_conv, gWihT, gWhhT, gbih, gbhh, hx);
    }

    gstart_kernel<<<4, 256, 0, stream>>>(batch, gst);
    for (int s = 0; s < 3; ++s) {
        lstm_kernel<<<N_GRAPHS, 64, 0, stream>>>(lWihT, lWhhT, lbih, lbhh, qstar, hl, cl);
        attn_kernel<<<N_GRAPHS, 64, 0, stream>>>(hx, qstar, gst);
    }

    bn_kernel<<<128, 64, 0, stream>>>(qstar, bng, bnb, bno);
    mlp1_kernel<<<dim3(N_GRAPHS, 2), 256, 0, stream>>>(bno, Wm1, bm1, y1);
    mlp2_kernel<<<N_GRAPHS, 256, 0, stream>>>(y1, Wm2, bm2, y2);
    pred_kernel<<<N_GRAPHS, 64, 0, stream>>>(y2, Wp, bp, out);
}

// Round 3
// 1077.158 us; speedup vs baseline: 1.4257x; 1.4257x over previous
//
#include <hip/hip_runtime.h>
#include <hip/hip_bf16.h>
#include <cstdint>
#include <cstddef>

#define N_NODES 20000
#define N_EDGES 40000
#define N_GRAPHS 800
#define ATOM 64
#define CONV 128
#define MLP1D 512
#define MLP2D 256
#define NOUT 34

typedef unsigned short u16;
typedef short short8 __attribute__((ext_vector_type(8)));
typedef float f32x4 __attribute__((ext_vector_type(4)));

__device__ __forceinline__ float bf2f(u16 u) {
    union { unsigned int i; float f; } v; v.i = ((unsigned int)u) << 16; return v.f;
}
__device__ __forceinline__ u16 f2bf(float f) {
    union { float f; unsigned int i; } v; v.f = f;
    unsigned int r = v.i + 0x7FFFu + ((v.i >> 16) & 1u);
    return (u16)(r >> 16);
}
__device__ __forceinline__ short fbf(float f) {
    union { __hip_bfloat16 b; short s; } u;
    u.b = __float2bfloat16(f);
    return u.s;
}
__device__ __forceinline__ float sigm(float x) { return 1.f / (1.f + expf(-x)); }

// ---------------- prep kernels ----------------

// dst[c*rows + r] = src[r*cols + c]
__global__ void transpose_f32(float* __restrict__ dst, const float* __restrict__ src,
                              int rows, int cols) {
    int i = blockIdx.x * 256 + threadIdx.x;
    if (i >= rows * cols) return;
    int r = i / cols, c = i % cols;
    dst[c * rows + r] = src[i];
}

// Bg[c][kh][mat][ft][lane][8] bf16; c<128: W_c[k][f]=We2[c][k*64+f]; c=128: be2[k*64+f]
// k = kh*32 + (lane>>4)*8 + j, f = ft*16 + (lane&15); mat0=hi, mat1=lo (split-bf16)
__global__ void bgprep(u16* __restrict__ Bg, const float* __restrict__ We2,
                       const float* __restrict__ be2) {
    int idx = blockIdx.x * 256 + threadIdx.x;          // [c][kh][ft][lane][j]
    if (idx >= 129 * 2 * 4 * 512) return;
    int j = idx & 7, lane = (idx >> 3) & 63, ft = (idx >> 9) & 3;
    int kh = (idx >> 11) & 1, c = idx >> 12;
    int k = kh * 32 + (lane >> 4) * 8 + j;
    int f = ft * 16 + (lane & 15);
    float v = (c < 128) ? We2[(size_t)c * 4096 + k * 64 + f] : be2[k * 64 + f];
    u16 hi = f2bf(v);
    u16 lo = f2bf(v - bf2f(hi));
    size_t o = (size_t)c * 8192 + (size_t)kh * 4096 + ft * 512 + lane * 8 + j;
    Bg[o] = hi;
    Bg[o + 2048] = lo;
}

// x = relu(x_feat @ W_lin + b_lin) -> hx f32, xbf bf16. 4 nodes/block.
__global__ __launch_bounds__(256) void lin_kernel(const float* __restrict__ xf,
    const float* __restrict__ W, const float* __restrict__ b,
    float* __restrict__ hx, u16* __restrict__ xbf) {
    __shared__ float xr[4][64];
    int ln = threadIdx.x >> 6, j = threadIdx.x & 63;
    int n = (blockIdx.x << 2) + ln;
    xr[ln][j] = xf[(size_t)n * 64 + j];
    __syncthreads();
    float acc = b[j];
    for (int i = 0; i < 64; ++i) acc = fmaf(xr[ln][i], W[i * 64 + j], acc);
    float r = fmaxf(acc, 0.f);
    hx[(size_t)n * 64 + j] = r;
    xbf[(size_t)n * 64 + j] = f2bf(r);
}

// heT[c][e] = relu(edge_attr @ W_e1 + b_e1)^T, f32. Block = 64 edges, 4 waves.
__global__ __launch_bounds__(256) void heprep(const float* __restrict__ ea,
    const float* __restrict__ W, const float* __restrict__ b, float* __restrict__ heT) {
    __shared__ float eaL[64 * 17];
    int e0 = blockIdx.x * 64;
    for (int idx = threadIdx.x; idx < 1024; idx += 256) {
        int r = idx >> 4, i = idx & 15;
        eaL[r * 17 + i] = ea[(size_t)(e0 + r) * 16 + i];
    }
    __syncthreads();
    int w = threadIdx.x >> 6, lane = threadIdx.x & 63;
    for (int c = w; c < 128; c += 4) {
        float acc = b[c];
        #pragma unroll
        for (int i = 0; i < 16; ++i)
            acc = fmaf(eaL[lane * 17 + i], W[i * 128 + c], acc);
        heT[(size_t)c * N_EDGES + e0 + lane] = fmaxf(acc, 0.f);
    }
}

__global__ void fill1(float* __restrict__ p, int n) {
    int i = blockIdx.x * 256 + threadIdx.x;
    if (i < n) p[i] = 1.0f;
}

__global__ void deg_kernel(const int* __restrict__ dst, float* __restrict__ deg) {
    int i = blockIdx.x * 256 + threadIdx.x;
    if (i < N_EDGES) atomicAdd(&deg[dst[i]], 1.f);
}

__global__ void gstart_kernel(const int* __restrict__ batch, int* __restrict__ gstart) {
    int g = blockIdx.x * 256 + threadIdx.x;
    if (g > N_GRAPHS) return;
    if (g == N_GRAPHS) { gstart[g] = N_NODES; return; }
    int lo = 0, hi = N_NODES;
    while (lo < hi) { int mid = (lo + hi) >> 1; if (batch[mid] < g) lo = mid + 1; else hi = mid; }
    gstart[g] = lo;
}

// ---------------- message passing (register-resident MFMA) ----------------
// msg[e,f] = sum_c he[e,c] * (x[src_e] @ W_c)[f]; he folded into A-frag.
// Wave = 32 edges (et 0/1), all 64 f. No LDS, no barriers, no K-split.
__global__ __launch_bounds__(128, 2) void msg_v2(
    const u16* __restrict__ Bg, const float* __restrict__ heT,
    const u16* __restrict__ xbf, const int* __restrict__ src,
    const int* __restrict__ dst, float* __restrict__ agg)
{
    int lane = threadIdx.x & 63;
    int w = threadIdx.x >> 6;
    int lr = lane & 15, lk = lane >> 4;
    int m0 = blockIdx.x * 64 + w * 32;

    // persistent x (A-base) as floats: xf[et][kh][8]
    float xf[2][2][8];
    #pragma unroll
    for (int et = 0; et < 2; ++et) {
        int e = m0 + et * 16 + lr;
        const u16* xp = xbf + (size_t)src[e] * 64 + lk * 8;
        #pragma unroll
        for (int kh = 0; kh < 2; ++kh)
            #pragma unroll
            for (int j = 0; j < 8; ++j)
                xf[et][kh][j] = bf2f(xp[kh * 32 + j]);
    }

    f32x4 acc[2][4] = {};
    const float* hp = heT + m0;
    const u16* bp = Bg + lane * 8;

    for (int c = 0; c < 129; ++c) {
        float h0 = hp[lr];
        float h1 = hp[16 + lr];
        short8 as0[2], as1[2];
        #pragma unroll
        for (int kh = 0; kh < 2; ++kh)
            #pragma unroll
            for (int j = 0; j < 8; ++j) {
                as0[kh][j] = fbf(h0 * xf[0][kh][j]);
                as1[kh][j] = fbf(h1 * xf[1][kh][j]);
            }
        #pragma unroll
        for (int kh = 0; kh < 2; ++kh) {
            const u16* bk = bp + kh * 4096;
            short8 bh0 = *(const short8*)(bk);
            short8 bh1 = *(const short8*)(bk + 512);
            short8 bh2 = *(const short8*)(bk + 1024);
            short8 bh3 = *(const short8*)(bk + 1536);
            short8 bl0 = *(const short8*)(bk + 2048);
            short8 bl1 = *(const short8*)(bk + 2560);
            short8 bl2 = *(const short8*)(bk + 3072);
            short8 bl3 = *(const short8*)(bk + 3584);
            acc[0][0] = __builtin_amdgcn_mfma_f32_16x16x32_bf16(as0[kh], bh0, acc[0][0], 0, 0, 0);
            acc[0][1] = __builtin_amdgcn_mfma_f32_16x16x32_bf16(as0[kh], bh1, acc[0][1], 0, 0, 0);
            acc[0][2] = __builtin_amdgcn_mfma_f32_16x16x32_bf16(as0[kh], bh2, acc[0][2], 0, 0, 0);
            acc[0][3] = __builtin_amdgcn_mfma_f32_16x16x32_bf16(as0[kh], bh3, acc[0][3], 0, 0, 0);
            acc[1][0] = __builtin_amdgcn_mfma_f32_16x16x32_bf16(as1[kh], bh0, acc[1][0], 0, 0, 0);
            acc[1][1] = __builtin_amdgcn_mfma_f32_16x16x32_bf16(as1[kh], bh1, acc[1][1], 0, 0, 0);
            acc[1][2] = __builtin_amdgcn_mfma_f32_16x16x32_bf16(as1[kh], bh2, acc[1][2], 0, 0, 0);
            acc[1][3] = __builtin_amdgcn_mfma_f32_16x16x32_bf16(as1[kh], bh3, acc[1][3], 0, 0, 0);
            acc[0][0] = __builtin_amdgcn_mfma_f32_16x16x32_bf16(as0[kh], bl0, acc[0][0], 0, 0, 0);
            acc[0][1] = __builtin_amdgcn_mfma_f32_16x16x32_bf16(as0[kh], bl1, acc[0][1], 0, 0, 0);
            acc[0][2] = __builtin_amdgcn_mfma_f32_16x16x32_bf16(as0[kh], bl2, acc[0][2], 0, 0, 0);
            acc[0][3] = __builtin_amdgcn_mfma_f32_16x16x32_bf16(as0[kh], bl3, acc[0][3], 0, 0, 0);
            acc[1][0] = __builtin_amdgcn_mfma_f32_16x16x32_bf16(as1[kh], bl0, acc[1][0], 0, 0, 0);
            acc[1][1] = __builtin_amdgcn_mfma_f32_16x16x32_bf16(as1[kh], bl1, acc[1][1], 0, 0, 0);
            acc[1][2] = __builtin_amdgcn_mfma_f32_16x16x32_bf16(as1[kh], bl2, acc[1][2], 0, 0, 0);
            acc[1][3] = __builtin_amdgcn_mfma_f32_16x16x32_bf16(as1[kh], bl3, acc[1][3], 0, 0, 0);
        }
        hp += N_EDGES;
        bp += 8192;
    }

    // scatter into agg: D row = edge (lk*4+r2), col = f (ft*16+lr)
    #pragma unroll
    for (int et = 0; et < 2; ++et)
        #pragma unroll
        for (int r2 = 0; r2 < 4; ++r2) {
            int e = m0 + et * 16 + lk * 4 + r2;
            int dv = dst[e];
            float* ap = agg + (size_t)dv * 64 + lr;
            atomicAdd(ap,      acc[et][0][r2]);
            atomicAdd(ap + 16, acc[et][1][r2]);
            atomicAdd(ap + 32, acc[et][2][r2]);
            atomicAdd(ap + 48, acc[et][3][r2]);
        }
}

// agg -> mean -> +b_conv -> relu -> GRU; updates hx (f32) and xbf (bf16). 4 nodes/block.
__global__ __launch_bounds__(256) void gru_kernel(const float* __restrict__ agg,
    const float* __restrict__ deg, const float* __restrict__ bconv,
    const float* __restrict__ WihT, const float* __restrict__ WhhT,   // [64][192]
    const float* __restrict__ bih, const float* __restrict__ bhh,
    float* __restrict__ hx, u16* __restrict__ xbf) {
    __shared__ float mh[4][2][64];
    int ln = threadIdx.x >> 6, j = threadIdx.x & 63;
    int n = (blockIdx.x << 2) + ln;
    float dg = fmaxf(deg[n], 1.f);
    float m = fmaxf(agg[(size_t)n * 64 + j] / dg + bconv[j], 0.f);
    float h = hx[(size_t)n * 64 + j];
    mh[ln][0][j] = m; mh[ln][1][j] = h;
    __syncthreads();
    float gri = bih[j], gzi = bih[64 + j], gni = bih[128 + j];
    float grh = bhh[j], gzh = bhh[64 + j], gnh = bhh[128 + j];
    for (int i = 0; i < 64; ++i) {
        float mi = mh[ln][0][i], hi = mh[ln][1][i];
        gri = fmaf(mi, WihT[i * 192 + j], gri);
        gzi = fmaf(mi, WihT[i * 192 + 64 + j], gzi);
        gni = fmaf(mi, WihT[i * 192 + 128 + j], gni);
        grh = fmaf(hi, WhhT[i * 192 + j], grh);
        gzh = fmaf(hi, WhhT[i * 192 + 64 + j], gzh);
        gnh = fmaf(hi, WhhT[i * 192 + 128 + j], gnh);
    }
    float rr = sigm(gri + grh);
    float zz = sigm(gzi + gzh);
    float nn = tanhf(gni + rr * gnh);
    float hnew = (1.f - zz) * nn + zz * h;
    hx[(size_t)n * 64 + j] = hnew;
    xbf[(size_t)n * 64 + j] = f2bf(hnew);
}

// ---------------- Set2Set ----------------
__global__ void lstm_kernel(const float* __restrict__ WihT,  // [128][256]
    const float* __restrict__ WhhT,                          // [64][256]
    const float* __restrict__ bih, const float* __restrict__ bhh,
    float* __restrict__ qstar, float* __restrict__ hl, float* __restrict__ cl) {
    __shared__ float qs[128], hs[64];
    int g = blockIdx.x, j = threadIdx.x;
    qs[j] = qstar[g * 128 + j];
    qs[64 + j] = qstar[g * 128 + 64 + j];
    hs[j] = hl[g * 64 + j];
    __syncthreads();
    float g0 = bih[j] + bhh[j];
    float g1 = bih[64 + j] + bhh[64 + j];
    float g2 = bih[128 + j] + bhh[128 + j];
    float g3 = bih[192 + j] + bhh[192 + j];
    for (int i = 0; i < 128; ++i) {
        float q = qs[i];
        g0 = fmaf(q, WihT[i * 256 + j], g0);
        g1 = fmaf(q, WihT[i * 256 + 64 + j], g1);
        g2 = fmaf(q, WihT[i * 256 + 128 + j], g2);
        g3 = fmaf(q, WihT[i * 256 + 192 + j], g3);
    }
    for (int i = 0; i < 64; ++i) {
        float hh = hs[i];
        g0 = fmaf(hh, WhhT[i * 256 + j], g0);
        g1 = fmaf(hh, WhhT[i * 256 + 64 + j], g1);
        g2 = fmaf(hh, WhhT[i * 256 + 128 + j], g2);
        g3 = fmaf(hh, WhhT[i * 256 + 192 + j], g3);
    }
    float ig = sigm(g0), fg = sigm(g1), cg = tanhf(g2), og = sigm(g3);
    float c = fg * cl[g * 64 + j] + ig * cg;
    cl[g * 64 + j] = c;
    float h = og * tanhf(c);
    hl[g * 64 + j] = h;
    qstar[g * 128 + j] = h;
}

// per-graph softmax attention readout; one wave per graph
__global__ void attn_kernel(const float* __restrict__ x, float* __restrict__ qstar,
                            const int* __restrict__ gstart) {
    int g = blockIdx.x, l = threadIdx.x;
    int s0 = gstart[g], s1 = gstart[g + 1];
    float q = qstar[g * 128 + l];
    float emax = -3.0e38f;
    for (int n = s0; n < s1; ++n) {
        float v = x[(size_t)n * 64 + l] * q;
        for (int o = 32; o; o >>= 1) v += __shfl_xor(v, o);
        emax = fmaxf(emax, v);
    }
    float esum = 0.f, racc = 0.f;
    for (int n = s0; n < s1; ++n) {
        float xv = x[(size_t)n * 64 + l];
        float v = xv * q;
        for (int o = 32; o; o >>= 1) v += __shfl_xor(v, o);
        float ww = expf(v - emax);
        esum += ww;
        racc = fmaf(ww, xv, racc);
    }
    qstar[g * 128 + 64 + l] = (s1 > s0) ? (racc / esum) : 0.f;
}

// ---------------- head ----------------
__global__ void bn_kernel(const float* __restrict__ qs, const float* __restrict__ gamma,
                          const float* __restrict__ beta, float* __restrict__ out) {
    int c = blockIdx.x, l = threadIdx.x;
    float s = 0.f, ss = 0.f;
    for (int r = l; r < N_GRAPHS; r += 64) {
        float v = qs[r * 128 + c];
        s += v; ss += v * v;
    }
    for (int o = 32; o; o >>= 1) { s += __shfl_xor(s, o); ss += __shfl_xor(ss, o); }
    float mu = s * (1.f / N_GRAPHS);
    float var = ss * (1.f / N_GRAPHS) - mu * mu;
    float inv = rsqrtf(var + 1e-5f);
    float ga = gamma[c], be = beta[c];
    for (int r = l; r < N_GRAPHS; r += 64)
        out[r * 128 + c] = ga * (qs[r * 128 + c] - mu) * inv + be;
}

__global__ __launch_bounds__(256) void mlp1_kernel(const float* __restrict__ in,
    const float* __restrict__ W, const float* __restrict__ b, float* __restrict__ out) {
    __shared__ float row[128];
    int r = blockIdx.x, o = blockIdx.y * 256 + threadIdx.x;
    if (threadIdx.x < 128) row[threadIdx.x] = in[r * 128 + threadIdx.x];
    __syncthreads();
    float acc = b[o];
    for (int i = 0; i < 128; ++i) acc = fmaf(row[i], W[i * MLP1D + o], acc);
    out[r * MLP1D + o] = fmaxf(acc, 0.f);
}

__global__ __launch_bounds__(256) void mlp2_kernel(const float* __restrict__ in,
    const float* __restrict__ W, const float* __restrict__ b, float* __restrict__ out) {
    __shared__ float row[512];
    int r = blockIdx.x, t = threadIdx.x;
    row[t] = in[r * MLP1D + t];
    row[256 + t] = in[r * MLP1D + 256 + t];
    __syncthreads();
    float acc = b[t];
    for (int i = 0; i < 512; ++i) acc = fmaf(row[i], W[i * MLP2D + t], acc);
    out[r * MLP2D + t] = fmaxf(acc, 0.f);
}

__global__ void pred_kernel(const float* __restrict__ y2, const float* __restrict__ W,
    const float* __restrict__ b, float* __restrict__ out) {
    __shared__ float row[256];
    int r = blockIdx.x, t = threadIdx.x;
    for (int i = t; i < 256; i += 64) row[i] = y2[r * MLP2D + i];
    __syncthreads();
    if (t < NOUT) {
        float acc = b[t];
        for (int i = 0; i < 256; ++i) acc = fmaf(row[i], W[i * NOUT + t], acc);
        out[r * NOUT + t] = acc;
    }
}

// ---------------- launch ----------------
extern "C" void kernel_launch(void* const* d_in, const int* in_sizes, int n_in,
                              void* d_out, int out_size, void* d_ws, size_t ws_size,
                              hipStream_t stream) {
    (void)in_sizes; (void)n_in; (void)out_size; (void)ws_size;
    const float* x_feat    = (const float*)d_in[0];
    const float* edge_attr = (const float*)d_in[1];
    const int*   eidx      = (const int*)d_in[2];
    const int*   batch     = (const int*)d_in[3];
    const float* W_lin = (const float*)d_in[4];
    const float* b_lin = (const float*)d_in[5];
    const float* W_e1  = (const float*)d_in[6];
    const float* b_e1  = (const float*)d_in[7];
    const float* W_e2  = (const float*)d_in[8];
    const float* b_e2  = (const float*)d_in[9];
    const float* b_conv= (const float*)d_in[10];
    const float* gWih  = (const float*)d_in[11];
    const float* gWhh  = (const float*)d_in[12];
    const float* gbih  = (const float*)d_in[13];
    const float* gbhh  = (const float*)d_in[14];
    const float* lWih  = (const float*)d_in[15];
    const float* lWhh  = (const float*)d_in[16];
    const float* lbih  = (const float*)d_in[17];
    const float* lbhh  = (const float*)d_in[18];
    const float* bng   = (const float*)d_in[19];
    const float* bnb   = (const float*)d_in[20];
    const float* Wm1   = (const float*)d_in[21];
    const float* bm1   = (const float*)d_in[22];
    const float* Wm2   = (const float*)d_in[23];
    const float* bm2   = (const float*)d_in[24];
    const float* Wp    = (const float*)d_in[25];
    const float* bp    = (const float*)d_in[26];
    float* out = (float*)d_out;

    const int* src = eidx;
    const int* dst = eidx + N_EDGES;

    char* w = (char*)d_ws;
    size_t off = 0;
    auto alloc = [&](size_t bytes) -> char* {
        char* p = w + off; off += (bytes + 255) & ~(size_t)255; return p;
    };
    u16*   Bg    = (u16*)alloc((size_t)129 * 8192 * 2);          // 2.11 MB
    float* heT   = (float*)alloc((size_t)129 * N_EDGES * 4);     // 20.6 MB
    u16*   xbf   = (u16*)alloc((size_t)N_NODES * 64 * 2);        // 2.56 MB
    float* hx    = (float*)alloc((size_t)N_NODES * 64 * 4);      // 5.12 MB
    float* agg   = (float*)alloc((size_t)N_NODES * 64 * 4);      // 5.12 MB
    float* deg   = (float*)alloc((size_t)N_NODES * 4);
    float* gWihT = (float*)alloc(192 * 64 * 4);
    float* gWhhT = (float*)alloc(192 * 64 * 4);
    float* lWihT = (float*)alloc(256 * 128 * 4);
    float* lWhhT = (float*)alloc(256 * 64 * 4);
    float* qstar = (float*)alloc((size_t)N_GRAPHS * 128 * 4);
    float* hl    = (float*)alloc((size_t)N_GRAPHS * 64 * 4);
    float* cl    = (float*)alloc((size_t)N_GRAPHS * 64 * 4);
    int*   gst   = (int*)alloc((N_GRAPHS + 1) * 4);
    float* bno   = (float*)alloc((size_t)N_GRAPHS * 128 * 4);
    float* y1    = (float*)alloc((size_t)N_GRAPHS * MLP1D * 4);
    float* y2    = (float*)alloc((size_t)N_GRAPHS * MLP2D * 4);
    // total ~36 MB

    hipMemsetAsync(deg, 0, (size_t)N_NODES * 4, stream);
    hipMemsetAsync(qstar, 0, (size_t)N_GRAPHS * 128 * 4, stream);
    hipMemsetAsync(hl, 0, (size_t)N_GRAPHS * 64 * 4, stream);
    hipMemsetAsync(cl, 0, (size_t)N_GRAPHS * 64 * 4, stream);

    transpose_f32<<<(192 * 64 + 255) / 256, 256, 0, stream>>>(gWihT, gWih, 192, 64);
    transpose_f32<<<(192 * 64 + 255) / 256, 256, 0, stream>>>(gWhhT, gWhh, 192, 64);
    transpose_f32<<<(256 * 128 + 255) / 256, 256, 0, stream>>>(lWihT, lWih, 256, 128);
    transpose_f32<<<(256 * 64 + 255) / 256, 256, 0, stream>>>(lWhhT, lWhh, 256, 64);
    bgprep<<<(129 * 2 * 4 * 512 + 255) / 256, 256, 0, stream>>>(Bg, W_e2, b_e2);
    lin_kernel<<<N_NODES / 4, 256, 0, stream>>>(x_feat, W_lin, b_lin, hx, xbf);
    heprep<<<N_EDGES / 64, 256, 0, stream>>>(edge_attr, W_e1, b_e1, heT);
    fill1<<<(N_EDGES + 255) / 256, 256, 0, stream>>>(heT + (size_t)128 * N_EDGES, N_EDGES);
    deg_kernel<<<(N_EDGES + 255) / 256, 256, 0, stream>>>(dst, deg);

    for (int r = 0; r < 3; ++r) {
        hipMemsetAsync(agg, 0, (size_t)N_NODES * 64 * 4, stream);
        msg_v2<<<N_EDGES / 64, 128, 0, stream>>>(Bg, heT, xbf, src, dst, agg);
        gru_kernel<<<N_NODES / 4, 256, 0, stream>>>(agg, deg, b_conv, gWihT, gWhhT, gbih, gbhh, hx, xbf);
    }

    gstart_kernel<<<4, 256, 0, stream>>>(batch, gst);
    for (int s = 0; s < 3; ++s) {
        lstm_kernel<<<N_GRAPHS, 64, 0, stream>>>(lWihT, lWhhT, lbih, lbhh, qstar, hl, cl);
        attn_kernel<<<N_GRAPHS, 64, 0, stream>>>(hx, qstar, gst);
    }

    bn_kernel<<<128, 64, 0, stream>>>(qstar, bng, bnb, bno);
    mlp1_kernel<<<dim3(N_GRAPHS, 2), 256, 0, stream>>>(bno, Wm1, bm1, y1);
    mlp2_kernel<<<N_GRAPHS, 256, 0, stream>>>(y1, Wm2, bm2, y2);
    pred_kernel<<<N_GRAPHS, 64, 0, stream>>>(y2, Wp, bp, out);
}

// Round 4
// 787.695 us; speedup vs baseline: 1.9496x; 1.3675x over previous
//
#include <hip/hip_runtime.h>
#include <hip/hip_bf16.h>
#include <cstdint>
#include <cstddef>

#define N_NODES 20000
#define N_EDGES 40000
#define N_GRAPHS 800
#define ATOM 64
#define CONV 128
#define MLP1D 512
#define MLP2D 256
#define NOUT 34

typedef unsigned short u16;
typedef short short8 __attribute__((ext_vector_type(8)));
typedef float f32x4 __attribute__((ext_vector_type(4)));

__device__ __forceinline__ float bf2f(u16 u) {
    union { unsigned int i; float f; } v; v.i = ((unsigned int)u) << 16; return v.f;
}
__device__ __forceinline__ u16 f2bf(float f) {
    union { float f; unsigned int i; } v; v.f = f;
    unsigned int r = v.i + 0x7FFFu + ((v.i >> 16) & 1u);
    return (u16)(r >> 16);
}
__device__ __forceinline__ short fbf(float f) {
    union { __hip_bfloat16 b; short s; } u;
    u.b = __float2bfloat16(f);
    return u.s;
}
__device__ __forceinline__ float sigm(float x) { return 1.f / (1.f + expf(-x)); }

// ---------------- prep kernels ----------------

// dst[c*rows + r] = src[r*cols + c]
__global__ void transpose_f32(float* __restrict__ dst, const float* __restrict__ src,
                              int rows, int cols) {
    int i = blockIdx.x * 256 + threadIdx.x;
    if (i >= rows * cols) return;
    int r = i / cols, c = i % cols;
    dst[c * rows + r] = src[i];
}

// Bg[c][kh][mat][ft][lane][8] bf16; c<128: W_c[k][f]=We2[c][k*64+f]; c=128: be2[k*64+f]
// k = kh*32 + (lane>>4)*8 + j, f = ft*16 + (lane&15); mat0=hi, mat1=lo (split-bf16)
__global__ void bgprep(u16* __restrict__ Bg, const float* __restrict__ We2,
                       const float* __restrict__ be2) {
    int idx = blockIdx.x * 256 + threadIdx.x;          // [c][kh][ft][lane][j]
    if (idx >= 129 * 2 * 4 * 512) return;
    int j = idx & 7, lane = (idx >> 3) & 63, ft = (idx >> 9) & 3;
    int kh = (idx >> 11) & 1, c = idx >> 12;
    int k = kh * 32 + (lane >> 4) * 8 + j;
    int f = ft * 16 + (lane & 15);
    float v = (c < 128) ? We2[(size_t)c * 4096 + k * 64 + f] : be2[k * 64 + f];
    u16 hi = f2bf(v);
    u16 lo = f2bf(v - bf2f(hi));
    size_t o = (size_t)c * 8192 + (size_t)kh * 4096 + ft * 512 + lane * 8 + j;
    Bg[o] = hi;
    Bg[o + 2048] = lo;
}

// x = relu(x_feat @ W_lin + b_lin) -> hx f32, xbf bf16. 4 nodes/block.
__global__ __launch_bounds__(256) void lin_kernel(const float* __restrict__ xf,
    const float* __restrict__ W, const float* __restrict__ b,
    float* __restrict__ hx, u16* __restrict__ xbf) {
    __shared__ float xr[4][64];
    int ln = threadIdx.x >> 6, j = threadIdx.x & 63;
    int n = (blockIdx.x << 2) + ln;
    xr[ln][j] = xf[(size_t)n * 64 + j];
    __syncthreads();
    float acc = b[j];
    for (int i = 0; i < 64; ++i) acc = fmaf(xr[ln][i], W[i * 64 + j], acc);
    float r = fmaxf(acc, 0.f);
    hx[(size_t)n * 64 + j] = r;
    xbf[(size_t)n * 64 + j] = f2bf(r);
}

// heT[c][e] = relu(edge_attr @ W_e1 + b_e1)^T, f32. Block = 64 edges, 4 waves.
__global__ __launch_bounds__(256) void heprep(const float* __restrict__ ea,
    const float* __restrict__ W, const float* __restrict__ b, float* __restrict__ heT) {
    __shared__ float eaL[64 * 17];
    int e0 = blockIdx.x * 64;
    for (int idx = threadIdx.x; idx < 1024; idx += 256) {
        int r = idx >> 4, i = idx & 15;
        eaL[r * 17 + i] = ea[(size_t)(e0 + r) * 16 + i];
    }
    __syncthreads();
    int w = threadIdx.x >> 6, lane = threadIdx.x & 63;
    for (int c = w; c < 128; c += 4) {
        float acc = b[c];
        #pragma unroll
        for (int i = 0; i < 16; ++i)
            acc = fmaf(eaL[lane * 17 + i], W[i * 128 + c], acc);
        heT[(size_t)c * N_EDGES + e0 + lane] = fmaxf(acc, 0.f);
    }
}

__global__ void fill1(float* __restrict__ p, int n) {
    int i = blockIdx.x * 256 + threadIdx.x;
    if (i < n) p[i] = 1.0f;
}

__global__ void deg_kernel(const int* __restrict__ dst, float* __restrict__ deg) {
    int i = blockIdx.x * 256 + threadIdx.x;
    if (i < N_EDGES) atomicAdd(&deg[dst[i]], 1.f);
}

__global__ void gstart_kernel(const int* __restrict__ batch, int* __restrict__ gstart) {
    int g = blockIdx.x * 256 + threadIdx.x;
    if (g > N_GRAPHS) return;
    if (g == N_GRAPHS) { gstart[g] = N_NODES; return; }
    int lo = 0, hi = N_NODES;
    while (lo < hi) { int mid = (lo + hi) >> 1; if (batch[mid] < g) lo = mid + 1; else hi = mid; }
    gstart[g] = lo;
}

// ---------------- message passing (register-resident MFMA, 4-way K-split) ----------------
// msg[e,f] = sum_c he[e,c] * (x[src_e] @ W_c)[f]; he folded into A-frag.
// Wave = 32 edges, all 64 f. blockIdx.y = K-split (c-range); atomics accumulate.
__global__ __launch_bounds__(128, 4) void msg_v3(
    const u16* __restrict__ Bg, const float* __restrict__ heT,
    const u16* __restrict__ xbf, const int* __restrict__ src,
    const int* __restrict__ dst, float* __restrict__ agg)
{
    int lane = threadIdx.x & 63;
    int w = threadIdx.x >> 6;
    int lr = lane & 15, lk = lane >> 4;
    int m0 = blockIdx.x * 64 + w * 32;
    int ks = blockIdx.y;                      // 0..3
    int c0 = (129 * ks) >> 2;
    int c1 = (129 * (ks + 1)) >> 2;           // 32,32,32,33 c's

    // persistent x (A-base) as floats: xf[et][kh][8]
    float xf[2][2][8];
    #pragma unroll
    for (int et = 0; et < 2; ++et) {
        int e = m0 + et * 16 + lr;
        const u16* xp = xbf + (size_t)src[e] * 64 + lk * 8;
        #pragma unroll
        for (int kh = 0; kh < 2; ++kh)
            #pragma unroll
            for (int j = 0; j < 8; ++j)
                xf[et][kh][j] = bf2f(xp[kh * 32 + j]);
    }

    f32x4 acc[2][4] = {};
    const float* hp = heT + (size_t)c0 * N_EDGES + m0;
    const u16* bp = Bg + (size_t)c0 * 8192 + lane * 8;

    for (int c = c0; c < c1; ++c) {
        float h0 = hp[lr];
        float h1 = hp[16 + lr];
        short8 as0[2], as1[2];
        #pragma unroll
        for (int kh = 0; kh < 2; ++kh)
            #pragma unroll
            for (int j = 0; j < 8; ++j) {
                as0[kh][j] = fbf(h0 * xf[0][kh][j]);
                as1[kh][j] = fbf(h1 * xf[1][kh][j]);
            }
        #pragma unroll
        for (int kh = 0; kh < 2; ++kh) {
            const u16* bk = bp + kh * 4096;
            short8 bh0 = *(const short8*)(bk);
            short8 bh1 = *(const short8*)(bk + 512);
            short8 bh2 = *(const short8*)(bk + 1024);
            short8 bh3 = *(const short8*)(bk + 1536);
            short8 bl0 = *(const short8*)(bk + 2048);
            short8 bl1 = *(const short8*)(bk + 2560);
            short8 bl2 = *(const short8*)(bk + 3072);
            short8 bl3 = *(const short8*)(bk + 3584);
            acc[0][0] = __builtin_amdgcn_mfma_f32_16x16x32_bf16(as0[kh], bh0, acc[0][0], 0, 0, 0);
            acc[0][1] = __builtin_amdgcn_mfma_f32_16x16x32_bf16(as0[kh], bh1, acc[0][1], 0, 0, 0);
            acc[0][2] = __builtin_amdgcn_mfma_f32_16x16x32_bf16(as0[kh], bh2, acc[0][2], 0, 0, 0);
            acc[0][3] = __builtin_amdgcn_mfma_f32_16x16x32_bf16(as0[kh], bh3, acc[0][3], 0, 0, 0);
            acc[1][0] = __builtin_amdgcn_mfma_f32_16x16x32_bf16(as1[kh], bh0, acc[1][0], 0, 0, 0);
            acc[1][1] = __builtin_amdgcn_mfma_f32_16x16x32_bf16(as1[kh], bh1, acc[1][1], 0, 0, 0);
            acc[1][2] = __builtin_amdgcn_mfma_f32_16x16x32_bf16(as1[kh], bh2, acc[1][2], 0, 0, 0);
            acc[1][3] = __builtin_amdgcn_mfma_f32_16x16x32_bf16(as1[kh], bh3, acc[1][3], 0, 0, 0);
            acc[0][0] = __builtin_amdgcn_mfma_f32_16x16x32_bf16(as0[kh], bl0, acc[0][0], 0, 0, 0);
            acc[0][1] = __builtin_amdgcn_mfma_f32_16x16x32_bf16(as0[kh], bl1, acc[0][1], 0, 0, 0);
            acc[0][2] = __builtin_amdgcn_mfma_f32_16x16x32_bf16(as0[kh], bl2, acc[0][2], 0, 0, 0);
            acc[0][3] = __builtin_amdgcn_mfma_f32_16x16x32_bf16(as0[kh], bl3, acc[0][3], 0, 0, 0);
            acc[1][0] = __builtin_amdgcn_mfma_f32_16x16x32_bf16(as1[kh], bl0, acc[1][0], 0, 0, 0);
            acc[1][1] = __builtin_amdgcn_mfma_f32_16x16x32_bf16(as1[kh], bl1, acc[1][1], 0, 0, 0);
            acc[1][2] = __builtin_amdgcn_mfma_f32_16x16x32_bf16(as1[kh], bl2, acc[1][2], 0, 0, 0);
            acc[1][3] = __builtin_amdgcn_mfma_f32_16x16x32_bf16(as1[kh], bl3, acc[1][3], 0, 0, 0);
        }
        hp += N_EDGES;
        bp += 8192;
    }

    // scatter partial msg into agg: D row = edge (lk*4+r2), col = f (ft*16+lr)
    #pragma unroll
    for (int et = 0; et < 2; ++et)
        #pragma unroll
        for (int r2 = 0; r2 < 4; ++r2) {
            int e = m0 + et * 16 + lk * 4 + r2;
            int dv = dst[e];
            float* ap = agg + (size_t)dv * 64 + lr;
            atomicAdd(ap,      acc[et][0][r2]);
            atomicAdd(ap + 16, acc[et][1][r2]);
            atomicAdd(ap + 32, acc[et][2][r2]);
            atomicAdd(ap + 48, acc[et][3][r2]);
        }
}

// agg -> mean -> +b_conv -> relu -> GRU; updates hx (f32) and xbf (bf16). 4 nodes/block.
__global__ __launch_bounds__(256) void gru_kernel(const float* __restrict__ agg,
    const float* __restrict__ deg, const float* __restrict__ bconv,
    const float* __restrict__ WihT, const float* __restrict__ WhhT,   // [64][192]
    const float* __restrict__ bih, const float* __restrict__ bhh,
    float* __restrict__ hx, u16* __restrict__ xbf) {
    __shared__ float mh[4][2][64];
    int ln = threadIdx.x >> 6, j = threadIdx.x & 63;
    int n = (blockIdx.x << 2) + ln;
    float dg = fmaxf(deg[n], 1.f);
    float m = fmaxf(agg[(size_t)n * 64 + j] / dg + bconv[j], 0.f);
    float h = hx[(size_t)n * 64 + j];
    mh[ln][0][j] = m; mh[ln][1][j] = h;
    __syncthreads();
    float gri = bih[j], gzi = bih[64 + j], gni = bih[128 + j];
    float grh = bhh[j], gzh = bhh[64 + j], gnh = bhh[128 + j];
    for (int i = 0; i < 64; ++i) {
        float mi = mh[ln][0][i], hi = mh[ln][1][i];
        gri = fmaf(mi, WihT[i * 192 + j], gri);
        gzi = fmaf(mi, WihT[i * 192 + 64 + j], gzi);
        gni = fmaf(mi, WihT[i * 192 + 128 + j], gni);
        grh = fmaf(hi, WhhT[i * 192 + j], grh);
        gzh = fmaf(hi, WhhT[i * 192 + 64 + j], gzh);
        gnh = fmaf(hi, WhhT[i * 192 + 128 + j], gnh);
    }
    float rr = sigm(gri + grh);
    float zz = sigm(gzi + gzh);
    float nn = tanhf(gni + rr * gnh);
    float hnew = (1.f - zz) * nn + zz * h;
    hx[(size_t)n * 64 + j] = hnew;
    xbf[(size_t)n * 64 + j] = f2bf(hnew);
}

// ---------------- fused Set2Set: 3 x (LSTM cell + softmax readout), 1 wave/graph ----------------
__global__ void s2s_kernel(const float* __restrict__ x, const int* __restrict__ gstart,
    const float* __restrict__ WihT,   // [128][256]
    const float* __restrict__ WhhT,   // [64][256]
    const float* __restrict__ bih, const float* __restrict__ bhh,
    float* __restrict__ qstar) {
    int g = blockIdx.x, j = threadIdx.x;   // 64 threads = 1 wave
    int s0 = gstart[g], s1 = gstart[g + 1];
    float qv = 0.f, rv = 0.f, h = 0.f, c = 0.f;
    for (int s = 0; s < 3; ++s) {
        float g0 = bih[j] + bhh[j];
        float g1 = bih[64 + j] + bhh[64 + j];
        float g2 = bih[128 + j] + bhh[128 + j];
        float g3 = bih[192 + j] + bhh[192 + j];
        for (int i = 0; i < 64; ++i) {
            float qi = __shfl(qv, i);
            g0 = fmaf(qi, WihT[i * 256 + j], g0);
            g1 = fmaf(qi, WihT[i * 256 + 64 + j], g1);
            g2 = fmaf(qi, WihT[i * 256 + 128 + j], g2);
            g3 = fmaf(qi, WihT[i * 256 + 192 + j], g3);
        }
        for (int i = 0; i < 64; ++i) {
            float ri = __shfl(rv, i);
            g0 = fmaf(ri, WihT[(64 + i) * 256 + j], g0);
            g1 = fmaf(ri, WihT[(64 + i) * 256 + 64 + j], g1);
            g2 = fmaf(ri, WihT[(64 + i) * 256 + 128 + j], g2);
            g3 = fmaf(ri, WihT[(64 + i) * 256 + 192 + j], g3);
        }
        for (int i = 0; i < 64; ++i) {
            float hi2 = __shfl(h, i);
            g0 = fmaf(hi2, WhhT[i * 256 + j], g0);
            g1 = fmaf(hi2, WhhT[i * 256 + 64 + j], g1);
            g2 = fmaf(hi2, WhhT[i * 256 + 128 + j], g2);
            g3 = fmaf(hi2, WhhT[i * 256 + 192 + j], g3);
        }
        float ig = sigm(g0), fg = sigm(g1), cg = tanhf(g2), og = sigm(g3);
        c = fg * c + ig * cg;
        h = og * tanhf(c);
        qv = h;
        // per-graph softmax attention readout
        float emax = -3.0e38f;
        for (int n = s0; n < s1; ++n) {
            float v = x[(size_t)n * 64 + j] * qv;
            for (int o = 32; o; o >>= 1) v += __shfl_xor(v, o);
            emax = fmaxf(emax, v);
        }
        float esum = 0.f, racc = 0.f;
        for (int n = s0; n < s1; ++n) {
            float xv = x[(size_t)n * 64 + j];
            float v = xv * qv;
            for (int o = 32; o; o >>= 1) v += __shfl_xor(v, o);
            float ww = expf(v - emax);
            esum += ww;
            racc = fmaf(ww, xv, racc);
        }
        rv = racc / esum;
    }
    qstar[g * 128 + j] = qv;
    qstar[g * 128 + 64 + j] = rv;
}

// ---------------- head ----------------
__global__ void bn_kernel(const float* __restrict__ qs, const float* __restrict__ gamma,
                          const float* __restrict__ beta, float* __restrict__ out) {
    int c = blockIdx.x, l = threadIdx.x;
    float s = 0.f, ss = 0.f;
    for (int r = l; r < N_GRAPHS; r += 64) {
        float v = qs[r * 128 + c];
        s += v; ss += v * v;
    }
    for (int o = 32; o; o >>= 1) { s += __shfl_xor(s, o); ss += __shfl_xor(ss, o); }
    float mu = s * (1.f / N_GRAPHS);
    float var = ss * (1.f / N_GRAPHS) - mu * mu;
    float inv = rsqrtf(var + 1e-5f);
    float ga = gamma[c], be = beta[c];
    for (int r = l; r < N_GRAPHS; r += 64)
        out[r * 128 + c] = ga * (qs[r * 128 + c] - mu) * inv + be;
}

__global__ __launch_bounds__(256) void mlp1_kernel(const float* __restrict__ in,
    const float* __restrict__ W, const float* __restrict__ b, float* __restrict__ out) {
    __shared__ float row[128];
    int r = blockIdx.x, o = blockIdx.y * 256 + threadIdx.x;
    if (threadIdx.x < 128) row[threadIdx.x] = in[r * 128 + threadIdx.x];
    __syncthreads();
    float acc = b[o];
    for (int i = 0; i < 128; ++i) acc = fmaf(row[i], W[i * MLP1D + o], acc);
    out[r * MLP1D + o] = fmaxf(acc, 0.f);
}

__global__ __launch_bounds__(256) void mlp2_kernel(const float* __restrict__ in,
    const float* __restrict__ W, const float* __restrict__ b, float* __restrict__ out) {
    __shared__ float row[512];
    int r = blockIdx.x, t = threadIdx.x;
    row[t] = in[r * MLP1D + t];
    row[256 + t] = in[r * MLP1D + 256 + t];
    __syncthreads();
    float acc = b[t];
    for (int i = 0; i < 512; ++i) acc = fmaf(row[i], W[i * MLP2D + t], acc);
    out[r * MLP2D + t] = fmaxf(acc, 0.f);
}

__global__ void pred_kernel(const float* __restrict__ y2, const float* __restrict__ W,
    const float* __restrict__ b, float* __restrict__ out) {
    __shared__ float row[256];
    int r = blockIdx.x, t = threadIdx.x;
    for (int i = t; i < 256; i += 64) row[i] = y2[r * MLP2D + i];
    __syncthreads();
    if (t < NOUT) {
        float acc = b[t];
        for (int i = 0; i < 256; ++i) acc = fmaf(row[i], W[i * NOUT + t], acc);
        out[r * NOUT + t] = acc;
    }
}

// ---------------- launch ----------------
extern "C" void kernel_launch(void* const* d_in, const int* in_sizes, int n_in,
                              void* d_out, int out_size, void* d_ws, size_t ws_size,
                              hipStream_t stream) {
    (void)in_sizes; (void)n_in; (void)out_size; (void)ws_size;
    const float* x_feat    = (const float*)d_in[0];
    const float* edge_attr = (const float*)d_in[1];
    const int*   eidx      = (const int*)d_in[2];
    const int*   batch     = (const int*)d_in[3];
    const float* W_lin = (const float*)d_in[4];
    const float* b_lin = (const float*)d_in[5];
    const float* W_e1  = (const float*)d_in[6];
    const float* b_e1  = (const float*)d_in[7];
    const float* W_e2  = (const float*)d_in[8];
    const float* b_e2  = (const float*)d_in[9];
    const float* b_conv= (const float*)d_in[10];
    const float* gWih  = (const float*)d_in[11];
    const float* gWhh  = (const float*)d_in[12];
    const float* gbih  = (const float*)d_in[13];
    const float* gbhh  = (const float*)d_in[14];
    const float* lWih  = (const float*)d_in[15];
    const float* lWhh  = (const float*)d_in[16];
    const float* lbih  = (const float*)d_in[17];
    const float* lbhh  = (const float*)d_in[18];
    const float* bng   = (const float*)d_in[19];
    const float* bnb   = (const float*)d_in[20];
    const float* Wm1   = (const float*)d_in[21];
    const float* bm1   = (const float*)d_in[22];
    const float* Wm2   = (const float*)d_in[23];
    const float* bm2   = (const float*)d_in[24];
    const float* Wp    = (const float*)d_in[25];
    const float* bp    = (const float*)d_in[26];
    float* out = (float*)d_out;

    const int* src = eidx;
    const int* dst = eidx + N_EDGES;

    char* w = (char*)d_ws;
    size_t off = 0;
    auto alloc = [&](size_t bytes) -> char* {
        char* p = w + off; off += (bytes + 255) & ~(size_t)255; return p;
    };
    u16*   Bg    = (u16*)alloc((size_t)129 * 8192 * 2);          // 2.11 MB
    float* heT   = (float*)alloc((size_t)129 * N_EDGES * 4);     // 20.6 MB
    u16*   xbf   = (u16*)alloc((size_t)N_NODES * 64 * 2);        // 2.56 MB
    float* hx    = (float*)alloc((size_t)N_NODES * 64 * 4);      // 5.12 MB
    float* agg   = (float*)alloc((size_t)N_NODES * 64 * 4);      // 5.12 MB
    float* deg   = (float*)alloc((size_t)N_NODES * 4);
    float* gWihT = (float*)alloc(192 * 64 * 4);
    float* gWhhT = (float*)alloc(192 * 64 * 4);
    float* lWihT = (float*)alloc(256 * 128 * 4);
    float* lWhhT = (float*)alloc(256 * 64 * 4);
    float* qstar = (float*)alloc((size_t)N_GRAPHS * 128 * 4);
    int*   gst   = (int*)alloc((N_GRAPHS + 1) * 4);
    float* bno   = (float*)alloc((size_t)N_GRAPHS * 128 * 4);
    float* y1    = (float*)alloc((size_t)N_GRAPHS * MLP1D * 4);
    float* y2    = (float*)alloc((size_t)N_GRAPHS * MLP2D * 4);
    // total ~36 MB

    hipMemsetAsync(deg, 0, (size_t)N_NODES * 4, stream);

    transpose_f32<<<(192 * 64 + 255) / 256, 256, 0, stream>>>(gWihT, gWih, 192, 64);
    transpose_f32<<<(192 * 64 + 255) / 256, 256, 0, stream>>>(gWhhT, gWhh, 192, 64);
    transpose_f32<<<(256 * 128 + 255) / 256, 256, 0, stream>>>(lWihT, lWih, 256, 128);
    transpose_f32<<<(256 * 64 + 255) / 256, 256, 0, stream>>>(lWhhT, lWhh, 256, 64);
    bgprep<<<(129 * 2 * 4 * 512 + 255) / 256, 256, 0, stream>>>(Bg, W_e2, b_e2);
    lin_kernel<<<N_NODES / 4, 256, 0, stream>>>(x_feat, W_lin, b_lin, hx, xbf);
    heprep<<<N_EDGES / 64, 256, 0, stream>>>(edge_attr, W_e1, b_e1, heT);
    fill1<<<(N_EDGES + 255) / 256, 256, 0, stream>>>(heT + (size_t)128 * N_EDGES, N_EDGES);
    deg_kernel<<<(N_EDGES + 255) / 256, 256, 0, stream>>>(dst, deg);
    gstart_kernel<<<4, 256, 0, stream>>>(batch, gst);

    for (int r = 0; r < 3; ++r) {
        hipMemsetAsync(agg, 0, (size_t)N_NODES * 64 * 4, stream);
        msg_v3<<<dim3(N_EDGES / 64, 4), 128, 0, stream>>>(Bg, heT, xbf, src, dst, agg);
        gru_kernel<<<N_NODES / 4, 256, 0, stream>>>(agg, deg, b_conv, gWihT, gWhhT, gbih, gbhh, hx, xbf);
    }

    s2s_kernel<<<N_GRAPHS, 64, 0, stream>>>(hx, gst, lWihT, lWhhT, lbih, lbhh, qstar);

    bn_kernel<<<128, 64, 0, stream>>>(qstar, bng, bnb, bno);
    mlp1_kernel<<<dim3(N_GRAPHS, 2), 256, 0, stream>>>(bno, Wm1, bm1, y1);
    mlp2_kernel<<<N_GRAPHS, 256, 0, stream>>>(y1, Wm2, bm2, y2);
    pred_kernel<<<N_GRAPHS, 64, 0, stream>>>(y2, Wp, bp, out);
}

// Round 5
// 754.636 us; speedup vs baseline: 2.0350x; 1.0438x over previous
//
#include <hip/hip_runtime.h>
#include <hip/hip_bf16.h>
#include <cstdint>
#include <cstddef>

#define N_NODES 20000
#define N_EDGES 40000
#define N_GRAPHS 800
#define ATOM 64
#define CONV 128
#define MLP1D 512
#define MLP2D 256
#define NOUT 34

typedef unsigned short u16;
typedef short short8 __attribute__((ext_vector_type(8)));
typedef float f32x4 __attribute__((ext_vector_type(4)));

__device__ __forceinline__ float bf2f(u16 u) {
    union { unsigned int i; float f; } v; v.i = ((unsigned int)u) << 16; return v.f;
}
__device__ __forceinline__ u16 f2bf(float f) {
    union { float f; unsigned int i; } v; v.f = f;
    unsigned int r = v.i + 0x7FFFu + ((v.i >> 16) & 1u);
    return (u16)(r >> 16);
}
__device__ __forceinline__ short fbf(float f) {
    union { __hip_bfloat16 b; short s; } u;
    u.b = __float2bfloat16(f);
    return u.s;
}
__device__ __forceinline__ float sigm(float x) { return 1.f / (1.f + expf(-x)); }

// ---------------- fused misc prep: 4 transposes + bias-row fill + gstart + deg ----------------
__global__ void prep_misc(const float* __restrict__ gWih, const float* __restrict__ gWhh,
                          const float* __restrict__ lWih, const float* __restrict__ lWhh,
                          float* __restrict__ gWihT, float* __restrict__ gWhhT,
                          float* __restrict__ lWihT, float* __restrict__ lWhhT,
                          float* __restrict__ heT_bias, const int* __restrict__ batch,
                          int* __restrict__ gstart, const int* __restrict__ dst,
                          float* __restrict__ deg) {
    int i = blockIdx.x * 256 + threadIdx.x;
    if (i < 12288) { int r = i / 64, c = i % 64; gWihT[c * 192 + r] = gWih[i]; return; }
    i -= 12288;
    if (i < 12288) { int r = i / 64, c = i % 64; gWhhT[c * 192 + r] = gWhh[i]; return; }
    i -= 12288;
    if (i < 32768) { int r = i / 128, c = i % 128; lWihT[c * 256 + r] = lWih[i]; return; }
    i -= 32768;
    if (i < 16384) { int r = i / 64, c = i % 64; lWhhT[c * 256 + r] = lWhh[i]; return; }
    i -= 16384;
    if (i < N_EDGES) { heT_bias[i] = 1.0f; return; }
    i -= N_EDGES;
    if (i <= N_GRAPHS) {
        if (i == N_GRAPHS) { gstart[i] = N_NODES; return; }
        int lo = 0, hi = N_NODES;
        while (lo < hi) { int mid = (lo + hi) >> 1; if (batch[mid] < i) lo = mid + 1; else hi = mid; }
        gstart[i] = lo;
        return;
    }
    i -= (N_GRAPHS + 1);
    if (i < N_EDGES) { atomicAdd(&deg[dst[i]], 1.f); return; }
}
#define PREP_TOTAL (12288 + 12288 + 32768 + 16384 + N_EDGES + (N_GRAPHS + 1) + N_EDGES)

// Bg[c][kh][mat][ft][lane][8] bf16; c<128: W_c[k][f]=We2[c][k*64+f]; c=128: be2[k*64+f]
// k = kh*32 + (lane>>4)*8 + j, f = ft*16 + (lane&15); mat0=hi, mat1=lo (split-bf16)
__global__ void bgprep(u16* __restrict__ Bg, const float* __restrict__ We2,
                       const float* __restrict__ be2) {
    int idx = blockIdx.x * 256 + threadIdx.x;          // [c][kh][ft][lane][j]
    if (idx >= 129 * 2 * 4 * 512) return;
    int j = idx & 7, lane = (idx >> 3) & 63, ft = (idx >> 9) & 3;
    int kh = (idx >> 11) & 1, c = idx >> 12;
    int k = kh * 32 + (lane >> 4) * 8 + j;
    int f = ft * 16 + (lane & 15);
    float v = (c < 128) ? We2[(size_t)c * 4096 + k * 64 + f] : be2[k * 64 + f];
    u16 hi = f2bf(v);
    u16 lo = f2bf(v - bf2f(hi));
    size_t o = (size_t)c * 8192 + (size_t)kh * 4096 + ft * 512 + lane * 8 + j;
    Bg[o] = hi;
    Bg[o + 2048] = lo;
}

// x = relu(x_feat @ W_lin + b_lin) -> hx f32, xbf bf16. 4 nodes/block.
__global__ __launch_bounds__(256) void lin_kernel(const float* __restrict__ xf,
    const float* __restrict__ W, const float* __restrict__ b,
    float* __restrict__ hx, u16* __restrict__ xbf) {
    __shared__ float xr[4][64];
    int ln = threadIdx.x >> 6, j = threadIdx.x & 63;
    int n = (blockIdx.x << 2) + ln;
    xr[ln][j] = xf[(size_t)n * 64 + j];
    __syncthreads();
    float acc = b[j];
    for (int i = 0; i < 64; ++i) acc = fmaf(xr[ln][i], W[i * 64 + j], acc);
    float r = fmaxf(acc, 0.f);
    hx[(size_t)n * 64 + j] = r;
    xbf[(size_t)n * 64 + j] = f2bf(r);
}

// heT[c][e] = relu(edge_attr @ W_e1 + b_e1)^T, f32. Block = 64 edges, 4 waves.
__global__ __launch_bounds__(256) void heprep(const float* __restrict__ ea,
    const float* __restrict__ W, const float* __restrict__ b, float* __restrict__ heT) {
    __shared__ float eaL[64 * 17];
    int e0 = blockIdx.x * 64;
    for (int idx = threadIdx.x; idx < 1024; idx += 256) {
        int r = idx >> 4, i = idx & 15;
        eaL[r * 17 + i] = ea[(size_t)(e0 + r) * 16 + i];
    }
    __syncthreads();
    int w = threadIdx.x >> 6, lane = threadIdx.x & 63;
    for (int c = w; c < 128; c += 4) {
        float acc = b[c];
        #pragma unroll
        for (int i = 0; i < 16; ++i)
            acc = fmaf(eaL[lane * 17 + i], W[i * 128 + c], acc);
        heT[(size_t)c * N_EDGES + e0 + lane] = fmaxf(acc, 0.f);
    }
}

// ---------------- message passing v4: E=4 edges-frags/wave, c-rotated, 8-way K-split ----------------
// msg[e,f] = sum_c he[e,c] * (x[src_e] @ W_c)[f]; he folded into A-frag.
// Wave (= block, 64 thr) handles 64 edges x all 64 f. blockIdx.y = K-split chunk.
// Per-block rotation of the c-iteration order spreads L2 slice traffic.
__global__ __launch_bounds__(64, 2) void msg_v4(
    const u16* __restrict__ Bg, const float* __restrict__ heT,
    const u16* __restrict__ xbf, const int* __restrict__ src,
    const int* __restrict__ dst, float* __restrict__ agg)
{
    int lane = threadIdx.x;
    int lr = lane & 15, lk = lane >> 4;
    int m0 = blockIdx.x * 64;
    int KS = gridDim.y;
    int ks = blockIdx.y;
    int c0 = (129 * ks) / KS;
    int c1 = (129 * (ks + 1)) / KS;
    int nc = c1 - c0;

    // persistent x[src] as f32: xf[et][kh][8]
    float xf[4][2][8];
    #pragma unroll
    for (int et = 0; et < 4; ++et) {
        int e = m0 + et * 16 + lr;
        const u16* xp = xbf + (size_t)src[e] * 64 + lk * 8;
        #pragma unroll
        for (int kh = 0; kh < 2; ++kh)
            #pragma unroll
            for (int j = 0; j < 8; ++j)
                xf[et][kh][j] = bf2f(xp[kh * 32 + j]);
    }

    f32x4 acc[4][4] = {};
    int rot = blockIdx.x % nc;

    for (int t = 0; t < nc; ++t) {
        int c = c0 + rot;
        ++rot; if (rot == nc) rot = 0;
        const float* hp = heT + (size_t)c * N_EDGES + m0;
        const u16* bp = Bg + (size_t)c * 8192 + lane * 8;

        float hv0 = hp[lr], hv1 = hp[16 + lr], hv2 = hp[32 + lr], hv3 = hp[48 + lr];
        short8 as0[2], as1[2], as2[2], as3[2];
        #pragma unroll
        for (int kh = 0; kh < 2; ++kh)
            #pragma unroll
            for (int j = 0; j < 8; ++j) {
                as0[kh][j] = fbf(hv0 * xf[0][kh][j]);
                as1[kh][j] = fbf(hv1 * xf[1][kh][j]);
                as2[kh][j] = fbf(hv2 * xf[2][kh][j]);
                as3[kh][j] = fbf(hv3 * xf[3][kh][j]);
            }
        #pragma unroll
        for (int kh = 0; kh < 2; ++kh) {
            const u16* bk = bp + kh * 4096;
            short8 bh0 = *(const short8*)(bk);
            short8 bh1 = *(const short8*)(bk + 512);
            short8 bh2 = *(const short8*)(bk + 1024);
            short8 bh3 = *(const short8*)(bk + 1536);
            short8 bl0 = *(const short8*)(bk + 2048);
            short8 bl1 = *(const short8*)(bk + 2560);
            short8 bl2 = *(const short8*)(bk + 3072);
            short8 bl3 = *(const short8*)(bk + 3584);
            acc[0][0] = __builtin_amdgcn_mfma_f32_16x16x32_bf16(as0[kh], bh0, acc[0][0], 0, 0, 0);
            acc[1][0] = __builtin_amdgcn_mfma_f32_16x16x32_bf16(as1[kh], bh0, acc[1][0], 0, 0, 0);
            acc[2][0] = __builtin_amdgcn_mfma_f32_16x16x32_bf16(as2[kh], bh0, acc[2][0], 0, 0, 0);
            acc[3][0] = __builtin_amdgcn_mfma_f32_16x16x32_bf16(as3[kh], bh0, acc[3][0], 0, 0, 0);
            acc[0][1] = __builtin_amdgcn_mfma_f32_16x16x32_bf16(as0[kh], bh1, acc[0][1], 0, 0, 0);
            acc[1][1] = __builtin_amdgcn_mfma_f32_16x16x32_bf16(as1[kh], bh1, acc[1][1], 0, 0, 0);
            acc[2][1] = __builtin_amdgcn_mfma_f32_16x16x32_bf16(as2[kh], bh1, acc[2][1], 0, 0, 0);
            acc[3][1] = __builtin_amdgcn_mfma_f32_16x16x32_bf16(as3[kh], bh1, acc[3][1], 0, 0, 0);
            acc[0][2] = __builtin_amdgcn_mfma_f32_16x16x32_bf16(as0[kh], bh2, acc[0][2], 0, 0, 0);
            acc[1][2] = __builtin_amdgcn_mfma_f32_16x16x32_bf16(as1[kh], bh2, acc[1][2], 0, 0, 0);
            acc[2][2] = __builtin_amdgcn_mfma_f32_16x16x32_bf16(as2[kh], bh2, acc[2][2], 0, 0, 0);
            acc[3][2] = __builtin_amdgcn_mfma_f32_16x16x32_bf16(as3[kh], bh2, acc[3][2], 0, 0, 0);
            acc[0][3] = __builtin_amdgcn_mfma_f32_16x16x32_bf16(as0[kh], bh3, acc[0][3], 0, 0, 0);
            acc[1][3] = __builtin_amdgcn_mfma_f32_16x16x32_bf16(as1[kh], bh3, acc[1][3], 0, 0, 0);
            acc[2][3] = __builtin_amdgcn_mfma_f32_16x16x32_bf16(as2[kh], bh3, acc[2][3], 0, 0, 0);
            acc[3][3] = __builtin_amdgcn_mfma_f32_16x16x32_bf16(as3[kh], bh3, acc[3][3], 0, 0, 0);
            acc[0][0] = __builtin_amdgcn_mfma_f32_16x16x32_bf16(as0[kh], bl0, acc[0][0], 0, 0, 0);
            acc[1][0] = __builtin_amdgcn_mfma_f32_16x16x32_bf16(as1[kh], bl0, acc[1][0], 0, 0, 0);
            acc[2][0] = __builtin_amdgcn_mfma_f32_16x16x32_bf16(as2[kh], bl0, acc[2][0], 0, 0, 0);
            acc[3][0] = __builtin_amdgcn_mfma_f32_16x16x32_bf16(as3[kh], bl0, acc[3][0], 0, 0, 0);
            acc[0][1] = __builtin_amdgcn_mfma_f32_16x16x32_bf16(as0[kh], bl1, acc[0][1], 0, 0, 0);
            acc[1][1] = __builtin_amdgcn_mfma_f32_16x16x32_bf16(as1[kh], bl1, acc[1][1], 0, 0, 0);
            acc[2][1] = __builtin_amdgcn_mfma_f32_16x16x32_bf16(as2[kh], bl1, acc[2][1], 0, 0, 0);
            acc[3][1] = __builtin_amdgcn_mfma_f32_16x16x32_bf16(as3[kh], bl1, acc[3][1], 0, 0, 0);
            acc[0][2] = __builtin_amdgcn_mfma_f32_16x16x32_bf16(as0[kh], bl2, acc[0][2], 0, 0, 0);
            acc[1][2] = __builtin_amdgcn_mfma_f32_16x16x32_bf16(as1[kh], bl2, acc[1][2], 0, 0, 0);
            acc[2][2] = __builtin_amdgcn_mfma_f32_16x16x32_bf16(as2[kh], bl2, acc[2][2], 0, 0, 0);
            acc[3][2] = __builtin_amdgcn_mfma_f32_16x16x32_bf16(as3[kh], bl2, acc[3][2], 0, 0, 0);
            acc[0][3] = __builtin_amdgcn_mfma_f32_16x16x32_bf16(as0[kh], bl3, acc[0][3], 0, 0, 0);
            acc[1][3] = __builtin_amdgcn_mfma_f32_16x16x32_bf16(as1[kh], bl3, acc[1][3], 0, 0, 0);
            acc[2][3] = __builtin_amdgcn_mfma_f32_16x16x32_bf16(as2[kh], bl3, acc[2][3], 0, 0, 0);
            acc[3][3] = __builtin_amdgcn_mfma_f32_16x16x32_bf16(as3[kh], bl3, acc[3][3], 0, 0, 0);
        }
    }

    // scatter partial msg into agg: D row = edge (lk*4+r2), col = f (ft*16+lr)
    #pragma unroll
    for (int et = 0; et < 4; ++et)
        #pragma unroll
        for (int r2 = 0; r2 < 4; ++r2) {
            int e = m0 + et * 16 + lk * 4 + r2;
            int dv = dst[e];
            float* ap = agg + (size_t)dv * 64 + lr;
            atomicAdd(ap,      acc[et][0][r2]);
            atomicAdd(ap + 16, acc[et][1][r2]);
            atomicAdd(ap + 32, acc[et][2][r2]);
            atomicAdd(ap + 48, acc[et][3][r2]);
        }
}

// agg -> mean -> +b_conv -> relu -> GRU; updates hx (f32) and xbf (bf16); zeroes agg for next round.
__global__ __launch_bounds__(256) void gru_kernel(float* __restrict__ agg,
    const float* __restrict__ deg, const float* __restrict__ bconv,
    const float* __restrict__ WihT, const float* __restrict__ WhhT,   // [64][192]
    const float* __restrict__ bih, const float* __restrict__ bhh,
    float* __restrict__ hx, u16* __restrict__ xbf) {
    __shared__ float mh[4][2][64];
    int ln = threadIdx.x >> 6, j = threadIdx.x & 63;
    int n = (blockIdx.x << 2) + ln;
    float dg = fmaxf(deg[n], 1.f);
    size_t idx = (size_t)n * 64 + j;
    float m = fmaxf(agg[idx] / dg + bconv[j], 0.f);
    agg[idx] = 0.f;                       // ready for next round's atomics
    float h = hx[idx];
    mh[ln][0][j] = m; mh[ln][1][j] = h;
    __syncthreads();
    float gri = bih[j], gzi = bih[64 + j], gni = bih[128 + j];
    float grh = bhh[j], gzh = bhh[64 + j], gnh = bhh[128 + j];
    for (int i = 0; i < 64; ++i) {
        float mi = mh[ln][0][i], hi = mh[ln][1][i];
        gri = fmaf(mi, WihT[i * 192 + j], gri);
        gzi = fmaf(mi, WihT[i * 192 + 64 + j], gzi);
        gni = fmaf(mi, WihT[i * 192 + 128 + j], gni);
        grh = fmaf(hi, WhhT[i * 192 + j], grh);
        gzh = fmaf(hi, WhhT[i * 192 + 64 + j], gzh);
        gnh = fmaf(hi, WhhT[i * 192 + 128 + j], gnh);
    }
    float rr = sigm(gri + grh);
    float zz = sigm(gzi + gzh);
    float nn = tanhf(gni + rr * gnh);
    float hnew = (1.f - zz) * nn + zz * h;
    hx[idx] = hnew;
    xbf[idx] = f2bf(hnew);
}

// ---------------- fused Set2Set: 3 x (LSTM cell + softmax readout), 1 wave/graph ----------------
__global__ void s2s_kernel(const float* __restrict__ x, const int* __restrict__ gstart,
    const float* __restrict__ WihT,   // [128][256]
    const float* __restrict__ WhhT,   // [64][256]
    const float* __restrict__ bih, const float* __restrict__ bhh,
    float* __restrict__ qstar) {
    int g = blockIdx.x, j = threadIdx.x;   // 64 threads = 1 wave
    int s0 = gstart[g], s1 = gstart[g + 1];
    float qv = 0.f, rv = 0.f, h = 0.f, c = 0.f;
    for (int s = 0; s < 3; ++s) {
        float g0 = bih[j] + bhh[j];
        float g1 = bih[64 + j] + bhh[64 + j];
        float g2 = bih[128 + j] + bhh[128 + j];
        float g3 = bih[192 + j] + bhh[192 + j];
        for (int i = 0; i < 64; ++i) {
            float qi = __shfl(qv, i);
            g0 = fmaf(qi, WihT[i * 256 + j], g0);
            g1 = fmaf(qi, WihT[i * 256 + 64 + j], g1);
            g2 = fmaf(qi, WihT[i * 256 + 128 + j], g2);
            g3 = fmaf(qi, WihT[i * 256 + 192 + j], g3);
        }
        for (int i = 0; i < 64; ++i) {
            float ri = __shfl(rv, i);
            g0 = fmaf(ri, WihT[(64 + i) * 256 + j], g0);
            g1 = fmaf(ri, WihT[(64 + i) * 256 + 64 + j], g1);
            g2 = fmaf(ri, WihT[(64 + i) * 256 + 128 + j], g2);
            g3 = fmaf(ri, WihT[(64 + i) * 256 + 192 + j], g3);
        }
        for (int i = 0; i < 64; ++i) {
            float hi2 = __shfl(h, i);
            g0 = fmaf(hi2, WhhT[i * 256 + j], g0);
            g1 = fmaf(hi2, WhhT[i * 256 + 64 + j], g1);
            g2 = fmaf(hi2, WhhT[i * 256 + 128 + j], g2);
            g3 = fmaf(hi2, WhhT[i * 256 + 192 + j], g3);
        }
        float ig = sigm(g0), fg = sigm(g1), cg = tanhf(g2), og = sigm(g3);
        c = fg * c + ig * cg;
        h = og * tanhf(c);
        qv = h;
        float emax = -3.0e38f;
        for (int n = s0; n < s1; ++n) {
            float v = x[(size_t)n * 64 + j] * qv;
            for (int o = 32; o; o >>= 1) v += __shfl_xor(v, o);
            emax = fmaxf(emax, v);
        }
        float esum = 0.f, racc = 0.f;
        for (int n = s0; n < s1; ++n) {
            float xv = x[(size_t)n * 64 + j];
            float v = xv * qv;
            for (int o = 32; o; o >>= 1) v += __shfl_xor(v, o);
            float ww = expf(v - emax);
            esum += ww;
            racc = fmaf(ww, xv, racc);
        }
        rv = racc / esum;
    }
    qstar[g * 128 + j] = qv;
    qstar[g * 128 + 64 + j] = rv;
}

// ---------------- head ----------------
__global__ void bn_kernel(const float* __restrict__ qs, const float* __restrict__ gamma,
                          const float* __restrict__ beta, float* __restrict__ out) {
    int c = blockIdx.x, l = threadIdx.x;
    float s = 0.f, ss = 0.f;
    for (int r = l; r < N_GRAPHS; r += 64) {
        float v = qs[r * 128 + c];
        s += v; ss += v * v;
    }
    for (int o = 32; o; o >>= 1) { s += __shfl_xor(s, o); ss += __shfl_xor(ss, o); }
    float mu = s * (1.f / N_GRAPHS);
    float var = ss * (1.f / N_GRAPHS) - mu * mu;
    float inv = rsqrtf(var + 1e-5f);
    float ga = gamma[c], be = beta[c];
    for (int r = l; r < N_GRAPHS; r += 64)
        out[r * 128 + c] = ga * (qs[r * 128 + c] - mu) * inv + be;
}

__global__ __launch_bounds__(256) void mlp1_kernel(const float* __restrict__ in,
    const float* __restrict__ W, const float* __restrict__ b, float* __restrict__ out) {
    __shared__ float row[128];
    int r = blockIdx.x, o = blockIdx.y * 256 + threadIdx.x;
    if (threadIdx.x < 128) row[threadIdx.x] = in[r * 128 + threadIdx.x];
    __syncthreads();
    float acc = b[o];
    for (int i = 0; i < 128; ++i) acc = fmaf(row[i], W[i * MLP1D + o], acc);
    out[r * MLP1D + o] = fmaxf(acc, 0.f);
}

__global__ __launch_bounds__(256) void mlp2_kernel(const float* __restrict__ in,
    const float* __restrict__ W, const float* __restrict__ b, float* __restrict__ out) {
    __shared__ float row[512];
    int r = blockIdx.x, t = threadIdx.x;
    row[t] = in[r * MLP1D + t];
    row[256 + t] = in[r * MLP1D + 256 + t];
    __syncthreads();
    float acc = b[t];
    for (int i = 0; i < 512; ++i) acc = fmaf(row[i], W[i * MLP2D + t], acc);
    out[r * MLP2D + t] = fmaxf(acc, 0.f);
}

__global__ void pred_kernel(const float* __restrict__ y2, const float* __restrict__ W,
    const float* __restrict__ b, float* __restrict__ out) {
    __shared__ float row[256];
    int r = blockIdx.x, t = threadIdx.x;
    for (int i = t; i < 256; i += 64) row[i] = y2[r * MLP2D + i];
    __syncthreads();
    if (t < NOUT) {
        float acc = b[t];
        for (int i = 0; i < 256; ++i) acc = fmaf(row[i], W[i * NOUT + t], acc);
        out[r * NOUT + t] = acc;
    }
}

// ---------------- launch ----------------
extern "C" void kernel_launch(void* const* d_in, const int* in_sizes, int n_in,
                              void* d_out, int out_size, void* d_ws, size_t ws_size,
                              hipStream_t stream) {
    (void)in_sizes; (void)n_in; (void)out_size; (void)ws_size;
    const float* x_feat    = (const float*)d_in[0];
    const float* edge_attr = (const float*)d_in[1];
    const int*   eidx      = (const int*)d_in[2];
    const int*   batch     = (const int*)d_in[3];
    const float* W_lin = (const float*)d_in[4];
    const float* b_lin = (const float*)d_in[5];
    const float* W_e1  = (const float*)d_in[6];
    const float* b_e1  = (const float*)d_in[7];
    const float* W_e2  = (const float*)d_in[8];
    const float* b_e2  = (const float*)d_in[9];
    const float* b_conv= (const float*)d_in[10];
    const float* gWih  = (const float*)d_in[11];
    const float* gWhh  = (const float*)d_in[12];
    const float* gbih  = (const float*)d_in[13];
    const float* gbhh  = (const float*)d_in[14];
    const float* lWih  = (const float*)d_in[15];
    const float* lWhh  = (const float*)d_in[16];
    const float* lbih  = (const float*)d_in[17];
    const float* lbhh  = (const float*)d_in[18];
    const float* bng   = (const float*)d_in[19];
    const float* bnb   = (const float*)d_in[20];
    const float* Wm1   = (const float*)d_in[21];
    const float* bm1   = (const float*)d_in[22];
    const float* Wm2   = (const float*)d_in[23];
    const float* bm2   = (const float*)d_in[24];
    const float* Wp    = (const float*)d_in[25];
    const float* bp    = (const float*)d_in[26];
    float* out = (float*)d_out;

    const int* src = eidx;
    const int* dst = eidx + N_EDGES;

    char* w = (char*)d_ws;
    size_t off = 0;
    auto alloc = [&](size_t bytes) -> char* {
        char* p = w + off; off += (bytes + 255) & ~(size_t)255; return p;
    };
    u16*   Bg    = (u16*)alloc((size_t)129 * 8192 * 2);          // 2.11 MB
    float* heT   = (float*)alloc((size_t)129 * N_EDGES * 4);     // 20.6 MB
    u16*   xbf   = (u16*)alloc((size_t)N_NODES * 64 * 2);        // 2.56 MB
    float* hx    = (float*)alloc((size_t)N_NODES * 64 * 4);      // 5.12 MB
    float* agg   = (float*)alloc((size_t)N_NODES * 64 * 4);      // 5.12 MB
    float* deg   = (float*)alloc((size_t)N_NODES * 4);
    float* gWihT = (float*)alloc(192 * 64 * 4);
    float* gWhhT = (float*)alloc(192 * 64 * 4);
    float* lWihT = (float*)alloc(256 * 128 * 4);
    float* lWhhT = (float*)alloc(256 * 64 * 4);
    float* qstar = (float*)alloc((size_t)N_GRAPHS * 128 * 4);
    int*   gst   = (int*)alloc((N_GRAPHS + 1) * 4);
    float* bno   = (float*)alloc((size_t)N_GRAPHS * 128 * 4);
    float* y1    = (float*)alloc((size_t)N_GRAPHS * MLP1D * 4);
    float* y2    = (float*)alloc((size_t)N_GRAPHS * MLP2D * 4);
    // total ~36 MB

    hipMemsetAsync(deg, 0, (size_t)N_NODES * 4, stream);
    hipMemsetAsync(agg, 0, (size_t)N_NODES * 64 * 4, stream);

    prep_misc<<<(PREP_TOTAL + 255) / 256, 256, 0, stream>>>(
        gWih, gWhh, lWih, lWhh, gWihT, gWhhT, lWihT, lWhhT,
        heT + (size_t)128 * N_EDGES, batch, gst, dst, deg);
    bgprep<<<(129 * 2 * 4 * 512 + 255) / 256, 256, 0, stream>>>(Bg, W_e2, b_e2);
    lin_kernel<<<N_NODES / 4, 256, 0, stream>>>(x_feat, W_lin, b_lin, hx, xbf);
    heprep<<<N_EDGES / 64, 256, 0, stream>>>(edge_attr, W_e1, b_e1, heT);

    for (int r = 0; r < 3; ++r) {
        msg_v4<<<dim3(N_EDGES / 64, 8), 64, 0, stream>>>(Bg, heT, xbf, src, dst, agg);
        gru_kernel<<<N_NODES / 4, 256, 0, stream>>>(agg, deg, b_conv, gWihT, gWhhT, gbih, gbhh, hx, xbf);
    }

    s2s_kernel<<<N_GRAPHS, 64, 0, stream>>>(hx, gst, lWihT, lWhhT, lbih, lbhh, qstar);

    bn_kernel<<<128, 64, 0, stream>>>(qstar, bng, bnb, bno);
    mlp1_kernel<<<dim3(N_GRAPHS, 2), 256, 0, stream>>>(bno, Wm1, bm1, y1);
    mlp2_kernel<<<N_GRAPHS, 256, 0, stream>>>(y1, Wm2, bm2, y2);
    pred_kernel<<<N_GRAPHS, 64, 0, stream>>>(y2, Wp, bp, out);
}

// Round 6
// 657.261 us; speedup vs baseline: 2.3364x; 1.1482x over previous
//
#include <hip/hip_runtime.h>
#include <hip/hip_bf16.h>
#include <cstdint>
#include <cstddef>

#define N_NODES 20000
#define N_EDGES 40000
#define EPAD 40192             // 157*256, padded edge count
#define N_GRAPHS 800
#define ATOM 64
#define MLP1D 512
#define MLP2D 256
#define NOUT 34

typedef _Float16 h2 __attribute__((ext_vector_type(2)));
typedef _Float16 half8 __attribute__((ext_vector_type(8)));
typedef float f32x4 __attribute__((ext_vector_type(4)));

__device__ __forceinline__ float sigm(float x) { return 1.f / (1.f + expf(-x)); }

// ---------------- fused prep: lin + heprep + Bf-build + misc ----------------
#define LIN_BLKS 5000
#define HEP_BLKS (EPAD / 64)                  // 628
#define BF_TOTAL (129 * 4096)                 // 528384
#define BF_BLKS ((BF_TOTAL + 255) / 256)      // 2064
#define MISC_TOTAL (12288 + 12288 + 32768 + 16384 + EPAD + (N_GRAPHS + 1) + N_EDGES)
#define MISC_BLKS ((MISC_TOTAL + 255) / 256)
#define PREP_BLKS (LIN_BLKS + HEP_BLKS + BF_BLKS + MISC_BLKS)

__global__ __launch_bounds__(256) void prep_all(
    const float* __restrict__ x_feat, const float* __restrict__ W_lin,
    const float* __restrict__ b_lin, float* __restrict__ hx, _Float16* __restrict__ xh,
    const float* __restrict__ ea, const float* __restrict__ W_e1,
    const float* __restrict__ b_e1, float* __restrict__ heT,
    const float* __restrict__ We2, const float* __restrict__ be2, _Float16* __restrict__ Bf,
    const float* __restrict__ gWih, const float* __restrict__ gWhh,
    const float* __restrict__ lWih, const float* __restrict__ lWhh,
    float* __restrict__ gWihT, float* __restrict__ gWhhT,
    float* __restrict__ lWihT, float* __restrict__ lWhhT,
    const int* __restrict__ batch, int* __restrict__ gstart,
    const int* __restrict__ dst, float* __restrict__ deg) {
    int bx = blockIdx.x;
    if (bx < LIN_BLKS) {
        // x = relu(x_feat @ W_lin + b_lin) -> hx f32, xh fp16. 4 nodes/block.
        __shared__ float xr[4][64];
        int ln = threadIdx.x >> 6, j = threadIdx.x & 63;
        int n = (bx << 2) + ln;
        xr[ln][j] = x_feat[(size_t)n * 64 + j];
        __syncthreads();
        float acc = b_lin[j];
        for (int i = 0; i < 64; ++i) acc = fmaf(xr[ln][i], W_lin[i * 64 + j], acc);
        float r = fmaxf(acc, 0.f);
        hx[(size_t)n * 64 + j] = r;
        xh[(size_t)n * 64 + j] = (_Float16)r;
        return;
    }
    bx -= LIN_BLKS;
    if (bx < HEP_BLKS) {
        // heT[c][e] = relu(ea @ W_e1 + b_e1)^T, stride EPAD. 64 edges/block.
        __shared__ float eaL[64 * 17];
        int e0 = bx * 64;
        for (int idx = threadIdx.x; idx < 1024; idx += 256) {
            int r = idx >> 4, i = idx & 15;
            int e = e0 + r;
            eaL[r * 17 + i] = (e < N_EDGES) ? ea[(size_t)e * 16 + i] : 0.f;
        }
        __syncthreads();
        int w = threadIdx.x >> 6, lane = threadIdx.x & 63;
        for (int c = w; c < 128; c += 4) {
            float acc = b_e1[c];
            #pragma unroll
            for (int i = 0; i < 16; ++i)
                acc = fmaf(eaL[lane * 17 + i], W_e1[i * 128 + c], acc);
            heT[(size_t)c * EPAD + e0 + lane] = fmaxf(acc, 0.f);
        }
        return;
    }
    bx -= HEP_BLKS;
    if (bx < BF_BLKS) {
        // Bf[c][kh][ft][lane][8] fp16: W_c[k][f] (c<128) or be2[k*64+f] (c=128)
        int idx = bx * 256 + threadIdx.x;
        if (idx >= BF_TOTAL) return;
        int j = idx & 7, lane = (idx >> 3) & 63, ft = (idx >> 9) & 3;
        int kh = (idx >> 11) & 1, c = idx >> 12;
        int k = kh * 32 + (lane >> 4) * 8 + j;
        int f = ft * 16 + (lane & 15);
        float v = (c < 128) ? We2[(size_t)c * 4096 + k * 64 + f] : be2[k * 64 + f];
        Bf[idx] = (_Float16)v;
        return;
    }
    bx -= BF_BLKS;
    {
        int i = bx * 256 + threadIdx.x;
        if (i < 12288) { int r = i / 64, c = i % 64; gWihT[c * 192 + r] = gWih[i]; return; }
        i -= 12288;
        if (i < 12288) { int r = i / 64, c = i % 64; gWhhT[c * 192 + r] = gWhh[i]; return; }
        i -= 12288;
        if (i < 32768) { int r = i / 128, c = i % 128; lWihT[c * 256 + r] = lWih[i]; return; }
        i -= 32768;
        if (i < 16384) { int r = i / 64, c = i % 64; lWhhT[c * 256 + r] = lWhh[i]; return; }
        i -= 16384;
        if (i < EPAD) { heT[(size_t)128 * EPAD + i] = 1.0f; return; }   // bias row
        i -= EPAD;
        if (i <= N_GRAPHS) {
            if (i == N_GRAPHS) { gstart[i] = N_NODES; return; }
            int lo = 0, hi = N_NODES;
            while (lo < hi) { int mid = (lo + hi) >> 1; if (batch[mid] < i) lo = mid + 1; else hi = mid; }
            gstart[i] = lo;
            return;
        }
        i -= (N_GRAPHS + 1);
        if (i < N_EDGES) { atomicAdd(&deg[dst[i]], 1.f); return; }
    }
}

// ---------------- message passing v5: fp16 single-matrix, L1-shared B, 4 waves/block ----------------
// msg[e,f] = sum_c he[e,c] * (x[src_e] @ W_c)[f]; he folded into A-frag (pk_mul_f16).
// Block = 256 thr = 4 waves x 64 edges = 256 edges. blockIdx.y = K-split over c.
// All waves walk c in the same order -> B (8 KB/c) is L1-shared per CU.
__global__ __launch_bounds__(256, 3) void msg_v5(
    const _Float16* __restrict__ Bf, const float* __restrict__ heT,
    const _Float16* __restrict__ xh, const int* __restrict__ src,
    const int* __restrict__ dst, float* __restrict__ agg)
{
    int tid = threadIdx.x;
    int w = tid >> 6, lane = tid & 63;
    int lr = lane & 15, lk = lane >> 4;
    int m0 = blockIdx.x * 256 + w * 64;
    int KS = gridDim.y, ks = blockIdx.y;
    int c0 = (129 * ks) / KS;
    int c1 = (129 * (ks + 1)) / KS;

    // persistent x[src] fragments as fp16 pairs: xf[et][kh][4]
    h2 xf[4][2][4];
    #pragma unroll
    for (int et = 0; et < 4; ++et) {
        int e = m0 + et * 16 + lr;               // < EPAD; src[e] valid (reads dst for pad)
        const _Float16* xp = xh + (size_t)src[e] * 64 + lk * 8;
        #pragma unroll
        for (int kh = 0; kh < 2; ++kh)
            #pragma unroll
            for (int j = 0; j < 4; ++j)
                xf[et][kh][j] = *(const h2*)(xp + kh * 32 + j * 2);
    }

    f32x4 acc[4][4] = {};
    const float* hp = heT + (size_t)c0 * EPAD + m0;
    const _Float16* bp = Bf + (size_t)c0 * 4096 + lane * 8;

    float hv0 = hp[lr], hv1 = hp[16 + lr], hv2 = hp[32 + lr], hv3 = hp[48 + lr];

    for (int c = c0; c < c1; ++c) {
        // prefetch next c's he under this c's compute
        float nv0 = 0.f, nv1 = 0.f, nv2 = 0.f, nv3 = 0.f;
        if (c + 1 < c1) {
            const float* hq = hp + EPAD;
            nv0 = hq[lr]; nv1 = hq[16 + lr]; nv2 = hq[32 + lr]; nv3 = hq[48 + lr];
        }
        _Float16 f0 = (_Float16)hv0, f1 = (_Float16)hv1, f2 = (_Float16)hv2, f3 = (_Float16)hv3;
        h2 hh[4] = { (h2){f0, f0}, (h2){f1, f1}, (h2){f2, f2}, (h2){f3, f3} };

        #pragma unroll
        for (int kh = 0; kh < 2; ++kh) {
            const _Float16* bk = bp + kh * 2048;
            half8 b0 = *(const half8*)(bk);
            half8 b1 = *(const half8*)(bk + 512);
            half8 b2 = *(const half8*)(bk + 1024);
            half8 b3 = *(const half8*)(bk + 1536);
            union A8 { h2 p[4]; half8 v; };
            A8 a0, a1, a2, a3;
            #pragma unroll
            for (int j = 0; j < 4; ++j) {
                a0.p[j] = hh[0] * xf[0][kh][j];
                a1.p[j] = hh[1] * xf[1][kh][j];
                a2.p[j] = hh[2] * xf[2][kh][j];
                a3.p[j] = hh[3] * xf[3][kh][j];
            }
            acc[0][0] = __builtin_amdgcn_mfma_f32_16x16x32_f16(a0.v, b0, acc[0][0], 0, 0, 0);
            acc[1][0] = __builtin_amdgcn_mfma_f32_16x16x32_f16(a1.v, b0, acc[1][0], 0, 0, 0);
            acc[2][0] = __builtin_amdgcn_mfma_f32_16x16x32_f16(a2.v, b0, acc[2][0], 0, 0, 0);
            acc[3][0] = __builtin_amdgcn_mfma_f32_16x16x32_f16(a3.v, b0, acc[3][0], 0, 0, 0);
            acc[0][1] = __builtin_amdgcn_mfma_f32_16x16x32_f16(a0.v, b1, acc[0][1], 0, 0, 0);
            acc[1][1] = __builtin_amdgcn_mfma_f32_16x16x32_f16(a1.v, b1, acc[1][1], 0, 0, 0);
            acc[2][1] = __builtin_amdgcn_mfma_f32_16x16x32_f16(a2.v, b1, acc[2][1], 0, 0, 0);
            acc[3][1] = __builtin_amdgcn_mfma_f32_16x16x32_f16(a3.v, b1, acc[3][1], 0, 0, 0);
            acc[0][2] = __builtin_amdgcn_mfma_f32_16x16x32_f16(a0.v, b2, acc[0][2], 0, 0, 0);
            acc[1][2] = __builtin_amdgcn_mfma_f32_16x16x32_f16(a1.v, b2, acc[1][2], 0, 0, 0);
            acc[2][2] = __builtin_amdgcn_mfma_f32_16x16x32_f16(a2.v, b2, acc[2][2], 0, 0, 0);
            acc[3][2] = __builtin_amdgcn_mfma_f32_16x16x32_f16(a3.v, b2, acc[3][2], 0, 0, 0);
            acc[0][3] = __builtin_amdgcn_mfma_f32_16x16x32_f16(a0.v, b3, acc[0][3], 0, 0, 0);
            acc[1][3] = __builtin_amdgcn_mfma_f32_16x16x32_f16(a1.v, b3, acc[1][3], 0, 0, 0);
            acc[2][3] = __builtin_amdgcn_mfma_f32_16x16x32_f16(a2.v, b3, acc[2][3], 0, 0, 0);
            acc[3][3] = __builtin_amdgcn_mfma_f32_16x16x32_f16(a3.v, b3, acc[3][3], 0, 0, 0);
        }
        hv0 = nv0; hv1 = nv1; hv2 = nv2; hv3 = nv3;
        hp += EPAD;
        bp += 4096;
    }

    // scatter partial msg into agg: D row = lk*4+r2 (edge), col = ft*16+lr (f)
    #pragma unroll
    for (int et = 0; et < 4; ++et)
        #pragma unroll
        for (int r2 = 0; r2 < 4; ++r2) {
            int e = m0 + et * 16 + lk * 4 + r2;
            if (e < N_EDGES) {
                int dv = dst[e];
                float* ap = agg + (size_t)dv * 64 + lr;
                atomicAdd(ap,      acc[et][0][r2]);
                atomicAdd(ap + 16, acc[et][1][r2]);
                atomicAdd(ap + 32, acc[et][2][r2]);
                atomicAdd(ap + 48, acc[et][3][r2]);
            }
        }
}

// agg -> mean -> +b_conv -> relu -> GRU; updates hx (f32) + xh (fp16); re-zeroes agg.
__global__ __launch_bounds__(256) void gru_kernel(float* __restrict__ agg,
    const float* __restrict__ deg, const float* __restrict__ bconv,
    const float* __restrict__ WihT, const float* __restrict__ WhhT,   // [64][192]
    const float* __restrict__ bih, const float* __restrict__ bhh,
    float* __restrict__ hx, _Float16* __restrict__ xh) {
    __shared__ float mh[4][2][64];
    int ln = threadIdx.x >> 6, j = threadIdx.x & 63;
    int n = (blockIdx.x << 2) + ln;
    float dg = fmaxf(deg[n], 1.f);
    size_t idx = (size_t)n * 64 + j;
    float m = fmaxf(agg[idx] / dg + bconv[j], 0.f);
    agg[idx] = 0.f;
    float h = hx[idx];
    mh[ln][0][j] = m; mh[ln][1][j] = h;
    __syncthreads();
    float gri = bih[j], gzi = bih[64 + j], gni = bih[128 + j];
    float grh = bhh[j], gzh = bhh[64 + j], gnh = bhh[128 + j];
    for (int i = 0; i < 64; ++i) {
        float mi = mh[ln][0][i], hi = mh[ln][1][i];
        gri = fmaf(mi, WihT[i * 192 + j], gri);
        gzi = fmaf(mi, WihT[i * 192 + 64 + j], gzi);
        gni = fmaf(mi, WihT[i * 192 + 128 + j], gni);
        grh = fmaf(hi, WhhT[i * 192 + j], grh);
        gzh = fmaf(hi, WhhT[i * 192 + 64 + j], gzh);
        gnh = fmaf(hi, WhhT[i * 192 + 128 + j], gnh);
    }
    float rr = sigm(gri + grh);
    float zz = sigm(gzi + gzh);
    float nn = tanhf(gni + rr * gnh);
    float hnew = (1.f - zz) * nn + zz * h;
    hx[idx] = hnew;
    xh[idx] = (_Float16)hnew;
}

// ---------------- fused Set2Set: 3 x (LSTM cell + softmax readout), 1 wave/graph ----------------
__global__ void s2s_kernel(const float* __restrict__ x, const int* __restrict__ gstart,
    const float* __restrict__ WihT,   // [128][256]
    const float* __restrict__ WhhT,   // [64][256]
    const float* __restrict__ bih, const float* __restrict__ bhh,
    float* __restrict__ qstar) {
    int g = blockIdx.x, j = threadIdx.x;
    int s0 = gstart[g], s1 = gstart[g + 1];
    float qv = 0.f, rv = 0.f, h = 0.f, c = 0.f;
    for (int s = 0; s < 3; ++s) {
        float g0 = bih[j] + bhh[j];
        float g1 = bih[64 + j] + bhh[64 + j];
        float g2 = bih[128 + j] + bhh[128 + j];
        float g3 = bih[192 + j] + bhh[192 + j];
        for (int i = 0; i < 64; ++i) {
            float qi = __shfl(qv, i);
            g0 = fmaf(qi, WihT[i * 256 + j], g0);
            g1 = fmaf(qi, WihT[i * 256 + 64 + j], g1);
            g2 = fmaf(qi, WihT[i * 256 + 128 + j], g2);
            g3 = fmaf(qi, WihT[i * 256 + 192 + j], g3);
        }
        for (int i = 0; i < 64; ++i) {
            float ri = __shfl(rv, i);
            g0 = fmaf(ri, WihT[(64 + i) * 256 + j], g0);
            g1 = fmaf(ri, WihT[(64 + i) * 256 + 64 + j], g1);
            g2 = fmaf(ri, WihT[(64 + i) * 256 + 128 + j], g2);
            g3 = fmaf(ri, WihT[(64 + i) * 256 + 192 + j], g3);
        }
        for (int i = 0; i < 64; ++i) {
            float hi2 = __shfl(h, i);
            g0 = fmaf(hi2, WhhT[i * 256 + j], g0);
            g1 = fmaf(hi2, WhhT[i * 256 + 64 + j], g1);
            g2 = fmaf(hi2, WhhT[i * 256 + 128 + j], g2);
            g3 = fmaf(hi2, WhhT[i * 256 + 192 + j], g3);
        }
        float ig = sigm(g0), fg = sigm(g1), cg = tanhf(g2), og = sigm(g3);
        c = fg * c + ig * cg;
        h = og * tanhf(c);
        qv = h;
        float emax = -3.0e38f;
        for (int n = s0; n < s1; ++n) {
            float v = x[(size_t)n * 64 + j] * qv;
            for (int o = 32; o; o >>= 1) v += __shfl_xor(v, o);
            emax = fmaxf(emax, v);
        }
        float esum = 0.f, racc = 0.f;
        for (int n = s0; n < s1; ++n) {
            float xv = x[(size_t)n * 64 + j];
            float v = xv * qv;
            for (int o = 32; o; o >>= 1) v += __shfl_xor(v, o);
            float ww = expf(v - emax);
            esum += ww;
            racc = fmaf(ww, xv, racc);
        }
        rv = racc / esum;
    }
    qstar[g * 128 + j] = qv;
    qstar[g * 128 + 64 + j] = rv;
}

// ---------------- head ----------------
__global__ void bn_kernel(const float* __restrict__ qs, const float* __restrict__ gamma,
                          const float* __restrict__ beta, float* __restrict__ out) {
    int c = blockIdx.x, l = threadIdx.x;
    float s = 0.f, ss = 0.f;
    for (int r = l; r < N_GRAPHS; r += 64) {
        float v = qs[r * 128 + c];
        s += v; ss += v * v;
    }
    for (int o = 32; o; o >>= 1) { s += __shfl_xor(s, o); ss += __shfl_xor(ss, o); }
    float mu = s * (1.f / N_GRAPHS);
    float var = ss * (1.f / N_GRAPHS) - mu * mu;
    float inv = rsqrtf(var + 1e-5f);
    float ga = gamma[c], be = beta[c];
    for (int r = l; r < N_GRAPHS; r += 64)
        out[r * 128 + c] = ga * (qs[r * 128 + c] - mu) * inv + be;
}

// fused MLP head: per graph, bno row -> y1(512) -> y2(256) -> out(34)
__global__ __launch_bounds__(512) void head_fused(const float* __restrict__ bno,
    const float* __restrict__ Wm1, const float* __restrict__ bm1,
    const float* __restrict__ Wm2, const float* __restrict__ bm2,
    const float* __restrict__ Wp, const float* __restrict__ bp,
    float* __restrict__ out) {
    __shared__ float row[128];
    __shared__ float y1[512];
    __shared__ float y2[256];
    int g = blockIdx.x, t = threadIdx.x;
    if (t < 128) row[t] = bno[g * 128 + t];
    __syncthreads();
    float acc = bm1[t];
    for (int i = 0; i < 128; ++i) acc = fmaf(row[i], Wm1[i * MLP1D + t], acc);
    y1[t] = fmaxf(acc, 0.f);
    __syncthreads();
    if (t < 256) {
        float a2 = bm2[t];
        for (int i = 0; i < 512; ++i) a2 = fmaf(y1[i], Wm2[i * MLP2D + t], a2);
        y2[t] = fmaxf(a2, 0.f);
    }
    __syncthreads();
    if (t < NOUT) {
        float a3 = bp[t];
        for (int i = 0; i < 256; ++i) a3 = fmaf(y2[i], Wp[i * NOUT + t], a3);
        out[g * NOUT + t] = a3;
    }
}

// ---------------- launch ----------------
extern "C" void kernel_launch(void* const* d_in, const int* in_sizes, int n_in,
                              void* d_out, int out_size, void* d_ws, size_t ws_size,
                              hipStream_t stream) {
    (void)in_sizes; (void)n_in; (void)out_size; (void)ws_size;
    const float* x_feat    = (const float*)d_in[0];
    const float* edge_attr = (const float*)d_in[1];
    const int*   eidx      = (const int*)d_in[2];
    const int*   batch     = (const int*)d_in[3];
    const float* W_lin = (const float*)d_in[4];
    const float* b_lin = (const float*)d_in[5];
    const float* W_e1  = (const float*)d_in[6];
    const float* b_e1  = (const float*)d_in[7];
    const float* W_e2  = (const float*)d_in[8];
    const float* b_e2  = (const float*)d_in[9];
    const float* b_conv= (const float*)d_in[10];
    const float* gWih  = (const float*)d_in[11];
    const float* gWhh  = (const float*)d_in[12];
    const float* gbih  = (const float*)d_in[13];
    const float* gbhh  = (const float*)d_in[14];
    const float* lWih  = (const float*)d_in[15];
    const float* lWhh  = (const float*)d_in[16];
    const float* lbih  = (const float*)d_in[17];
    const float* lbhh  = (const float*)d_in[18];
    const float* bng   = (const float*)d_in[19];
    const float* bnb   = (const float*)d_in[20];
    const float* Wm1   = (const float*)d_in[21];
    const float* bm1   = (const float*)d_in[22];
    const float* Wm2   = (const float*)d_in[23];
    const float* bm2   = (const float*)d_in[24];
    const float* Wp    = (const float*)d_in[25];
    const float* bp    = (const float*)d_in[26];
    float* out = (float*)d_out;

    const int* src = eidx;
    const int* dst = eidx + N_EDGES;

    char* w = (char*)d_ws;
    size_t off = 0;
    auto alloc = [&](size_t bytes) -> char* {
        char* p = w + off; off += (bytes + 255) & ~(size_t)255; return p;
    };
    _Float16* Bf   = (_Float16*)alloc((size_t)129 * 4096 * 2);     // 1.06 MB
    float* heT     = (float*)alloc((size_t)129 * EPAD * 4);        // 20.7 MB
    _Float16* xh   = (_Float16*)alloc((size_t)N_NODES * 64 * 2);   // 2.56 MB
    float* hx      = (float*)alloc((size_t)N_NODES * 64 * 4);      // 5.12 MB
    float* agg     = (float*)alloc((size_t)N_NODES * 64 * 4);      // 5.12 MB
    float* deg     = (float*)alloc((size_t)N_NODES * 4);
    float* gWihT   = (float*)alloc(192 * 64 * 4);
    float* gWhhT   = (float*)alloc(192 * 64 * 4);
    float* lWihT   = (float*)alloc(256 * 128 * 4);
    float* lWhhT   = (float*)alloc(256 * 64 * 4);
    float* qstar   = (float*)alloc((size_t)N_GRAPHS * 128 * 4);
    int*   gst     = (int*)alloc((N_GRAPHS + 1) * 4);
    float* bno     = (float*)alloc((size_t)N_GRAPHS * 128 * 4);
    // total ~36 MB

    hipMemsetAsync(deg, 0, (size_t)N_NODES * 4, stream);
    hipMemsetAsync(agg, 0, (size_t)N_NODES * 64 * 4, stream);

    prep_all<<<PREP_BLKS, 256, 0, stream>>>(
        x_feat, W_lin, b_lin, hx, xh,
        edge_attr, W_e1, b_e1, heT,
        W_e2, b_e2, Bf,
        gWih, gWhh, lWih, lWhh, gWihT, gWhhT, lWihT, lWhhT,
        batch, gst, dst, deg);

    for (int r = 0; r < 3; ++r) {
        msg_v5<<<dim3(EPAD / 256, 8), 256, 0, stream>>>(Bf, heT, xh, src, dst, agg);
        gru_kernel<<<N_NODES / 4, 256, 0, stream>>>(agg, deg, b_conv, gWihT, gWhhT, gbih, gbhh, hx, xh);
    }

    s2s_kernel<<<N_GRAPHS, 64, 0, stream>>>(hx, gst, lWihT, lWhhT, lbih, lbhh, qstar);

    bn_kernel<<<128, 64, 0, stream>>>(qstar, bng, bnb, bno);
    head_fused<<<N_GRAPHS, 512, 0, stream>>>(bno, Wm1, bm1, Wm2, bm2, Wp, bp, out);
}

// Round 7
// 638.878 us; speedup vs baseline: 2.4037x; 1.0288x over previous
//
#include <hip/hip_runtime.h>
#include <hip/hip_bf16.h>
#include <cstdint>
#include <cstddef>

#define N_NODES 20000
#define N_EDGES 40000
#define EPAD 40192             // 157*256, padded edge count
#define N_GRAPHS 800
#define ATOM 64
#define MLP1D 512
#define MLP2D 256
#define NOUT 34

typedef _Float16 h2 __attribute__((ext_vector_type(2)));
typedef _Float16 half8 __attribute__((ext_vector_type(8)));
typedef float f32x4 __attribute__((ext_vector_type(4)));

__device__ __forceinline__ float sigm(float x) { return 1.f / (1.f + expf(-x)); }

// ---------------- fused prep: lin + heprep + Bf-build + misc ----------------
#define LIN_BLKS 5000
#define HEP_BLKS (EPAD / 64)                  // 628
#define BF_TOTAL (129 * 4096)                 // 528384
#define BF_BLKS ((BF_TOTAL + 255) / 256)      // 2064
#define MISC_TOTAL (12288 + 12288 + 32768 + 16384 + EPAD + (N_GRAPHS + 1) + N_EDGES)
#define MISC_BLKS ((MISC_TOTAL + 255) / 256)
#define PREP_BLKS (LIN_BLKS + HEP_BLKS + BF_BLKS + MISC_BLKS)

__global__ __launch_bounds__(256) void prep_all(
    const float* __restrict__ x_feat, const float* __restrict__ W_lin,
    const float* __restrict__ b_lin, float* __restrict__ hx, _Float16* __restrict__ xh,
    const float* __restrict__ ea, const float* __restrict__ W_e1,
    const float* __restrict__ b_e1, float* __restrict__ heT,
    const float* __restrict__ We2, const float* __restrict__ be2, _Float16* __restrict__ Bf,
    const float* __restrict__ gWih, const float* __restrict__ gWhh,
    const float* __restrict__ lWih, const float* __restrict__ lWhh,
    float* __restrict__ gWihT, float* __restrict__ gWhhT,
    float* __restrict__ lWihT, float* __restrict__ lWhhT,
    const int* __restrict__ batch, int* __restrict__ gstart,
    const int* __restrict__ dst, float* __restrict__ deg) {
    int bx = blockIdx.x;
    if (bx < LIN_BLKS) {
        __shared__ float xr[4][64];
        int ln = threadIdx.x >> 6, j = threadIdx.x & 63;
        int n = (bx << 2) + ln;
        xr[ln][j] = x_feat[(size_t)n * 64 + j];
        __syncthreads();
        float acc = b_lin[j];
        for (int i = 0; i < 64; ++i) acc = fmaf(xr[ln][i], W_lin[i * 64 + j], acc);
        float r = fmaxf(acc, 0.f);
        hx[(size_t)n * 64 + j] = r;
        xh[(size_t)n * 64 + j] = (_Float16)r;
        return;
    }
    bx -= LIN_BLKS;
    if (bx < HEP_BLKS) {
        __shared__ float eaL[64 * 17];
        int e0 = bx * 64;
        for (int idx = threadIdx.x; idx < 1024; idx += 256) {
            int r = idx >> 4, i = idx & 15;
            int e = e0 + r;
            eaL[r * 17 + i] = (e < N_EDGES) ? ea[(size_t)e * 16 + i] : 0.f;
        }
        __syncthreads();
        int w = threadIdx.x >> 6, lane = threadIdx.x & 63;
        for (int c = w; c < 128; c += 4) {
            float acc = b_e1[c];
            #pragma unroll
            for (int i = 0; i < 16; ++i)
                acc = fmaf(eaL[lane * 17 + i], W_e1[i * 128 + c], acc);
            heT[(size_t)c * EPAD + e0 + lane] = fmaxf(acc, 0.f);
        }
        return;
    }
    bx -= HEP_BLKS;
    if (bx < BF_BLKS) {
        int idx = bx * 256 + threadIdx.x;
        if (idx >= BF_TOTAL) return;
        int j = idx & 7, lane = (idx >> 3) & 63, ft = (idx >> 9) & 3;
        int kh = (idx >> 11) & 1, c = idx >> 12;
        int k = kh * 32 + (lane >> 4) * 8 + j;
        int f = ft * 16 + (lane & 15);
        float v = (c < 128) ? We2[(size_t)c * 4096 + k * 64 + f] : be2[k * 64 + f];
        Bf[idx] = (_Float16)v;
        return;
    }
    bx -= BF_BLKS;
    {
        int i = bx * 256 + threadIdx.x;
        if (i < 12288) { int r = i / 64, c = i % 64; gWihT[c * 192 + r] = gWih[i]; return; }
        i -= 12288;
        if (i < 12288) { int r = i / 64, c = i % 64; gWhhT[c * 192 + r] = gWhh[i]; return; }
        i -= 12288;
        if (i < 32768) { int r = i / 128, c = i % 128; lWihT[c * 256 + r] = lWih[i]; return; }
        i -= 32768;
        if (i < 16384) { int r = i / 64, c = i % 64; lWhhT[c * 256 + r] = lWhh[i]; return; }
        i -= 16384;
        if (i < EPAD) { heT[(size_t)128 * EPAD + i] = 1.0f; return; }
        i -= EPAD;
        if (i <= N_GRAPHS) {
            if (i == N_GRAPHS) { gstart[i] = N_NODES; return; }
            int lo = 0, hi = N_NODES;
            while (lo < hi) { int mid = (lo + hi) >> 1; if (batch[mid] < i) lo = mid + 1; else hi = mid; }
            gstart[i] = lo;
            return;
        }
        i -= (N_GRAPHS + 1);
        if (i < N_EDGES) { atomicAdd(&deg[dst[i]], 1.f); return; }
    }
}

// ---------------- message passing v6: fp16, rotated c-order, reg double-buffer ----------------
// msg[e,f] = sum_c he[e,c] * (x[src_e] @ W_c)[f]; he folded into A-frag.
// Block = 4 waves x 64 edges. blockIdx.y = K-split chunk; per-block rotation of the
// c-order (modular) decorrelates cross-CU L2 streams; B + he for c+1 prefetched into
// registers under c's 32-MFMA cluster.
__global__ __launch_bounds__(256) void msg_v6(
    const _Float16* __restrict__ Bf, const float* __restrict__ heT,
    const _Float16* __restrict__ xh, const int* __restrict__ src,
    const int* __restrict__ dst, float* __restrict__ agg)
{
    int tid = threadIdx.x;
    int w = tid >> 6, lane = tid & 63;
    int lr = lane & 15, lk = lane >> 4;
    int m0 = blockIdx.x * 256 + w * 64;
    int KS = gridDim.y, ks = blockIdx.y;
    int c0 = (129 * ks) / KS;
    int c1 = (129 * (ks + 1)) / KS;
    int nc = c1 - c0;

    // persistent x[src] fragments as fp16 pairs
    h2 xf[4][2][4];
    #pragma unroll
    for (int et = 0; et < 4; ++et) {
        int e = m0 + et * 16 + lr;
        const _Float16* xp = xh + (size_t)src[e] * 64 + lk * 8;
        #pragma unroll
        for (int kh = 0; kh < 2; ++kh)
            #pragma unroll
            for (int j = 0; j < 4; ++j)
                xf[et][kh][j] = *(const h2*)(xp + kh * 32 + j * 2);
    }

    f32x4 acc[4][4] = {};

    int cur = blockIdx.x % nc;                 // rotation offset
    {
        // preload first c
    }
    const _Float16* bpc = Bf + (size_t)(c0 + cur) * 4096 + lane * 8;
    half8 bc[8];
    #pragma unroll
    for (int q = 0; q < 8; ++q) bc[q] = *(const half8*)(bpc + q * 512);
    const float* hpc = heT + (size_t)(c0 + cur) * EPAD + m0;
    float hv0 = hpc[lr], hv1 = hpc[16 + lr], hv2 = hpc[32 + lr], hv3 = hpc[48 + lr];

    for (int t = 0; t < nc; ++t) {
        int nxt = (cur + 1 == nc) ? 0 : cur + 1;
        // prefetch next c (wraps into valid range -> no guards)
        const _Float16* bpn = Bf + (size_t)(c0 + nxt) * 4096 + lane * 8;
        half8 bn[8];
        #pragma unroll
        for (int q = 0; q < 8; ++q) bn[q] = *(const half8*)(bpn + q * 512);
        const float* hpn = heT + (size_t)(c0 + nxt) * EPAD + m0;
        float nv0 = hpn[lr], nv1 = hpn[16 + lr], nv2 = hpn[32 + lr], nv3 = hpn[48 + lr];

        _Float16 f0 = (_Float16)hv0, f1 = (_Float16)hv1, f2 = (_Float16)hv2, f3 = (_Float16)hv3;
        h2 hh0 = (h2){f0, f0}, hh1 = (h2){f1, f1}, hh2 = (h2){f2, f2}, hh3 = (h2){f3, f3};

        #pragma unroll
        for (int kh = 0; kh < 2; ++kh) {
            union A8 { h2 p[4]; half8 v; };
            A8 a0, a1, a2, a3;
            #pragma unroll
            for (int j = 0; j < 4; ++j) {
                a0.p[j] = hh0 * xf[0][kh][j];
                a1.p[j] = hh1 * xf[1][kh][j];
                a2.p[j] = hh2 * xf[2][kh][j];
                a3.p[j] = hh3 * xf[3][kh][j];
            }
            acc[0][0] = __builtin_amdgcn_mfma_f32_16x16x32_f16(a0.v, bc[kh * 4 + 0], acc[0][0], 0, 0, 0);
            acc[1][0] = __builtin_amdgcn_mfma_f32_16x16x32_f16(a1.v, bc[kh * 4 + 0], acc[1][0], 0, 0, 0);
            acc[2][0] = __builtin_amdgcn_mfma_f32_16x16x32_f16(a2.v, bc[kh * 4 + 0], acc[2][0], 0, 0, 0);
            acc[3][0] = __builtin_amdgcn_mfma_f32_16x16x32_f16(a3.v, bc[kh * 4 + 0], acc[3][0], 0, 0, 0);
            acc[0][1] = __builtin_amdgcn_mfma_f32_16x16x32_f16(a0.v, bc[kh * 4 + 1], acc[0][1], 0, 0, 0);
            acc[1][1] = __builtin_amdgcn_mfma_f32_16x16x32_f16(a1.v, bc[kh * 4 + 1], acc[1][1], 0, 0, 0);
            acc[2][1] = __builtin_amdgcn_mfma_f32_16x16x32_f16(a2.v, bc[kh * 4 + 1], acc[2][1], 0, 0, 0);
            acc[3][1] = __builtin_amdgcn_mfma_f32_16x16x32_f16(a3.v, bc[kh * 4 + 1], acc[3][1], 0, 0, 0);
            acc[0][2] = __builtin_amdgcn_mfma_f32_16x16x32_f16(a0.v, bc[kh * 4 + 2], acc[0][2], 0, 0, 0);
            acc[1][2] = __builtin_amdgcn_mfma_f32_16x16x32_f16(a1.v, bc[kh * 4 + 2], acc[1][2], 0, 0, 0);
            acc[2][2] = __builtin_amdgcn_mfma_f32_16x16x32_f16(a2.v, bc[kh * 4 + 2], acc[2][2], 0, 0, 0);
            acc[3][2] = __builtin_amdgcn_mfma_f32_16x16x32_f16(a3.v, bc[kh * 4 + 2], acc[3][2], 0, 0, 0);
            acc[0][3] = __builtin_amdgcn_mfma_f32_16x16x32_f16(a0.v, bc[kh * 4 + 3], acc[0][3], 0, 0, 0);
            acc[1][3] = __builtin_amdgcn_mfma_f32_16x16x32_f16(a1.v, bc[kh * 4 + 3], acc[1][3], 0, 0, 0);
            acc[2][3] = __builtin_amdgcn_mfma_f32_16x16x32_f16(a2.v, bc[kh * 4 + 3], acc[2][3], 0, 0, 0);
            acc[3][3] = __builtin_amdgcn_mfma_f32_16x16x32_f16(a3.v, bc[kh * 4 + 3], acc[3][3], 0, 0, 0);
        }

        #pragma unroll
        for (int q = 0; q < 8; ++q) bc[q] = bn[q];
        hv0 = nv0; hv1 = nv1; hv2 = nv2; hv3 = nv3;
        cur = nxt;
    }

    // scatter partial msg into agg: D row = lk*4+r2 (edge), col = ft*16+lr (f)
    #pragma unroll
    for (int et = 0; et < 4; ++et)
        #pragma unroll
        for (int r2 = 0; r2 < 4; ++r2) {
            int e = m0 + et * 16 + lk * 4 + r2;
            if (e < N_EDGES) {
                int dv = dst[e];
                float* ap = agg + (size_t)dv * 64 + lr;
                atomicAdd(ap,      acc[et][0][r2]);
                atomicAdd(ap + 16, acc[et][1][r2]);
                atomicAdd(ap + 32, acc[et][2][r2]);
                atomicAdd(ap + 48, acc[et][3][r2]);
            }
        }
}

// agg -> mean -> +b_conv -> relu -> GRU; updates hx (f32) + xh (fp16); re-zeroes agg.
// Weight reads rotated per-block to avoid cross-CU L2 broadcast storms.
__global__ __launch_bounds__(256) void gru_kernel(float* __restrict__ agg,
    const float* __restrict__ deg, const float* __restrict__ bconv,
    const float* __restrict__ WihT, const float* __restrict__ WhhT,   // [64][192]
    const float* __restrict__ bih, const float* __restrict__ bhh,
    float* __restrict__ hx, _Float16* __restrict__ xh) {
    __shared__ float mh[4][2][64];
    int ln = threadIdx.x >> 6, j = threadIdx.x & 63;
    int n = (blockIdx.x << 2) + ln;
    float dg = fmaxf(deg[n], 1.f);
    size_t idx = (size_t)n * 64 + j;
    float m = fmaxf(agg[idx] / dg + bconv[j], 0.f);
    agg[idx] = 0.f;
    float h = hx[idx];
    mh[ln][0][j] = m; mh[ln][1][j] = h;
    __syncthreads();
    float gri = bih[j], gzi = bih[64 + j], gni = bih[128 + j];
    float grh = bhh[j], gzh = bhh[64 + j], gnh = bhh[128 + j];
    int rot = blockIdx.x & 63;
    for (int t = 0; t < 64; ++t) {
        int i = (t + rot) & 63;
        float mi = mh[ln][0][i], hi = mh[ln][1][i];
        gri = fmaf(mi, WihT[i * 192 + j], gri);
        gzi = fmaf(mi, WihT[i * 192 + 64 + j], gzi);
        gni = fmaf(mi, WihT[i * 192 + 128 + j], gni);
        grh = fmaf(hi, WhhT[i * 192 + j], grh);
        gzh = fmaf(hi, WhhT[i * 192 + 64 + j], gzh);
        gnh = fmaf(hi, WhhT[i * 192 + 128 + j], gnh);
    }
    float rr = sigm(gri + grh);
    float zz = sigm(gzi + gzh);
    float nn = tanhf(gni + rr * gnh);
    float hnew = (1.f - zz) * nn + zz * h;
    hx[idx] = hnew;
    xh[idx] = (_Float16)hnew;
}

// ---------------- fused Set2Set: 3 x (LSTM cell + softmax readout), 1 wave/graph ----------------
__global__ void s2s_kernel(const float* __restrict__ x, const int* __restrict__ gstart,
    const float* __restrict__ WihT,   // [128][256]
    const float* __restrict__ WhhT,   // [64][256]
    const float* __restrict__ bih, const float* __restrict__ bhh,
    float* __restrict__ qstar) {
    int g = blockIdx.x, j = threadIdx.x;
    int s0 = gstart[g], s1 = gstart[g + 1];
    int rot = g & 63;
    float qv = 0.f, rv = 0.f, h = 0.f, c = 0.f;
    for (int s = 0; s < 3; ++s) {
        float g0 = bih[j] + bhh[j];
        float g1 = bih[64 + j] + bhh[64 + j];
        float g2 = bih[128 + j] + bhh[128 + j];
        float g3 = bih[192 + j] + bhh[192 + j];
        for (int t = 0; t < 64; ++t) {
            int i = (t + rot) & 63;
            float qi = __shfl(qv, i);
            g0 = fmaf(qi, WihT[i * 256 + j], g0);
            g1 = fmaf(qi, WihT[i * 256 + 64 + j], g1);
            g2 = fmaf(qi, WihT[i * 256 + 128 + j], g2);
            g3 = fmaf(qi, WihT[i * 256 + 192 + j], g3);
        }
        for (int t = 0; t < 64; ++t) {
            int i = (t + rot) & 63;
            float ri = __shfl(rv, i);
            g0 = fmaf(ri, WihT[(64 + i) * 256 + j], g0);
            g1 = fmaf(ri, WihT[(64 + i) * 256 + 64 + j], g1);
            g2 = fmaf(ri, WihT[(64 + i) * 256 + 128 + j], g2);
            g3 = fmaf(ri, WihT[(64 + i) * 256 + 192 + j], g3);
        }
        for (int t = 0; t < 64; ++t) {
            int i = (t + rot) & 63;
            float hi2 = __shfl(h, i);
            g0 = fmaf(hi2, WhhT[i * 256 + j], g0);
            g1 = fmaf(hi2, WhhT[i * 256 + 64 + j], g1);
            g2 = fmaf(hi2, WhhT[i * 256 + 128 + j], g2);
            g3 = fmaf(hi2, WhhT[i * 256 + 192 + j], g3);
        }
        float ig = sigm(g0), fg = sigm(g1), cg = tanhf(g2), og = sigm(g3);
        c = fg * c + ig * cg;
        h = og * tanhf(c);
        qv = h;
        float emax = -3.0e38f;
        for (int n = s0; n < s1; ++n) {
            float v = x[(size_t)n * 64 + j] * qv;
            for (int o = 32; o; o >>= 1) v += __shfl_xor(v, o);
            emax = fmaxf(emax, v);
        }
        float esum = 0.f, racc = 0.f;
        for (int n = s0; n < s1; ++n) {
            float xv = x[(size_t)n * 64 + j];
            float v = xv * qv;
            for (int o = 32; o; o >>= 1) v += __shfl_xor(v, o);
            float ww = expf(v - emax);
            esum += ww;
            racc = fmaf(ww, xv, racc);
        }
        rv = racc / esum;
    }
    qstar[g * 128 + j] = qv;
    qstar[g * 128 + 64 + j] = rv;
}

// ---------------- head ----------------
__global__ void bn_kernel(const float* __restrict__ qs, const float* __restrict__ gamma,
                          const float* __restrict__ beta, float* __restrict__ out) {
    int c = blockIdx.x, l = threadIdx.x;
    float s = 0.f, ss = 0.f;
    for (int r = l; r < N_GRAPHS; r += 64) {
        float v = qs[r * 128 + c];
        s += v; ss += v * v;
    }
    for (int o = 32; o; o >>= 1) { s += __shfl_xor(s, o); ss += __shfl_xor(ss, o); }
    float mu = s * (1.f / N_GRAPHS);
    float var = ss * (1.f / N_GRAPHS) - mu * mu;
    float inv = rsqrtf(var + 1e-5f);
    float ga = gamma[c], be = beta[c];
    for (int r = l; r < N_GRAPHS; r += 64)
        out[r * 128 + c] = ga * (qs[r * 128 + c] - mu) * inv + be;
}

// fused MLP head: per graph, bno row -> y1(512) -> y2(256) -> out(34); rotated W reads
__global__ __launch_bounds__(512) void head_fused(const float* __restrict__ bno,
    const float* __restrict__ Wm1, const float* __restrict__ bm1,
    const float* __restrict__ Wm2, const float* __restrict__ bm2,
    const float* __restrict__ Wp, const float* __restrict__ bp,
    float* __restrict__ out) {
    __shared__ float row[128];
    __shared__ float y1[512];
    __shared__ float y2[256];
    int g = blockIdx.x, t = threadIdx.x;
    int rot = (g * 17) & 127;
    if (t < 128) row[t] = bno[g * 128 + t];
    __syncthreads();
    float acc = bm1[t];
    for (int s = 0; s < 128; ++s) {
        int i = (s + rot) & 127;
        acc = fmaf(row[i], Wm1[i * MLP1D + t], acc);
    }
    y1[t] = fmaxf(acc, 0.f);
    __syncthreads();
    if (t < 256) {
        float a2 = bm2[t];
        int rot2 = (g * 31) & 511;
        for (int s = 0; s < 512; ++s) {
            int i = (s + rot2) & 511;
            a2 = fmaf(y1[i], Wm2[i * MLP2D + t], a2);
        }
        y2[t] = fmaxf(a2, 0.f);
    }
    __syncthreads();
    if (t < NOUT) {
        float a3 = bp[t];
        int rot3 = (g * 13) & 255;
        for (int s = 0; s < 256; ++s) {
            int i = (s + rot3) & 255;
            a3 = fmaf(y2[i], Wp[i * NOUT + t], a3);
        }
        out[g * NOUT + t] = a3;
    }
}

// ---------------- launch ----------------
extern "C" void kernel_launch(void* const* d_in, const int* in_sizes, int n_in,
                              void* d_out, int out_size, void* d_ws, size_t ws_size,
                              hipStream_t stream) {
    (void)in_sizes; (void)n_in; (void)out_size; (void)ws_size;
    const float* x_feat    = (const float*)d_in[0];
    const float* edge_attr = (const float*)d_in[1];
    const int*   eidx      = (const int*)d_in[2];
    const int*   batch     = (const int*)d_in[3];
    const float* W_lin = (const float*)d_in[4];
    const float* b_lin = (const float*)d_in[5];
    const float* W_e1  = (const float*)d_in[6];
    const float* b_e1  = (const float*)d_in[7];
    const float* W_e2  = (const float*)d_in[8];
    const float* b_e2  = (const float*)d_in[9];
    const float* b_conv= (const float*)d_in[10];
    const float* gWih  = (const float*)d_in[11];
    const float* gWhh  = (const float*)d_in[12];
    const float* gbih  = (const float*)d_in[13];
    const float* gbhh  = (const float*)d_in[14];
    const float* lWih  = (const float*)d_in[15];
    const float* lWhh  = (const float*)d_in[16];
    const float* lbih  = (const float*)d_in[17];
    const float* lbhh  = (const float*)d_in[18];
    const float* bng   = (const float*)d_in[19];
    const float* bnb   = (const float*)d_in[20];
    const float* Wm1   = (const float*)d_in[21];
    const float* bm1   = (const float*)d_in[22];
    const float* Wm2   = (const float*)d_in[23];
    const float* bm2   = (const float*)d_in[24];
    const float* Wp    = (const float*)d_in[25];
    const float* bp    = (const float*)d_in[26];
    float* out = (float*)d_out;

    const int* src = eidx;
    const int* dst = eidx + N_EDGES;

    char* w = (char*)d_ws;
    size_t off = 0;
    auto alloc = [&](size_t bytes) -> char* {
        char* p = w + off; off += (bytes + 255) & ~(size_t)255; return p;
    };
    _Float16* Bf   = (_Float16*)alloc((size_t)129 * 4096 * 2);     // 1.06 MB
    float* heT     = (float*)alloc((size_t)129 * EPAD * 4);        // 20.7 MB
    _Float16* xh   = (_Float16*)alloc((size_t)N_NODES * 64 * 2);   // 2.56 MB
    float* hx      = (float*)alloc((size_t)N_NODES * 64 * 4);      // 5.12 MB
    float* agg     = (float*)alloc((size_t)N_NODES * 64 * 4);      // 5.12 MB
    float* deg     = (float*)alloc((size_t)N_NODES * 4);
    float* gWihT   = (float*)alloc(192 * 64 * 4);
    float* gWhhT   = (float*)alloc(192 * 64 * 4);
    float* lWihT   = (float*)alloc(256 * 128 * 4);
    float* lWhhT   = (float*)alloc(256 * 64 * 4);
    float* qstar   = (float*)alloc((size_t)N_GRAPHS * 128 * 4);
    int*   gst     = (int*)alloc((N_GRAPHS + 1) * 4);
    float* bno     = (float*)alloc((size_t)N_GRAPHS * 128 * 4);
    // total ~36 MB

    hipMemsetAsync(deg, 0, (size_t)N_NODES * 4, stream);
    hipMemsetAsync(agg, 0, (size_t)N_NODES * 64 * 4, stream);

    prep_all<<<PREP_BLKS, 256, 0, stream>>>(
        x_feat, W_lin, b_lin, hx, xh,
        edge_attr, W_e1, b_e1, heT,
        W_e2, b_e2, Bf,
        gWih, gWhh, lWih, lWhh, gWihT, gWhhT, lWihT, lWhhT,
        batch, gst, dst, deg);

    for (int r = 0; r < 3; ++r) {
        msg_v6<<<dim3(EPAD / 256, 8), 256, 0, stream>>>(Bf, heT, xh, src, dst, agg);
        gru_kernel<<<N_NODES / 4, 256, 0, stream>>>(agg, deg, b_conv, gWihT, gWhhT, gbih, gbhh, hx, xh);
    }

    s2s_kernel<<<N_GRAPHS, 64, 0, stream>>>(hx, gst, lWihT, lWhhT, lbih, lbhh, qstar);

    bn_kernel<<<128, 64, 0, stream>>>(qstar, bng, bnb, bno);
    head_fused<<<N_GRAPHS, 512, 0, stream>>>(bno, Wm1, bm1, Wm2, bm2, Wp, bp, out);
}